// Round 7
// baseline (161.070 us; speedup 1.0000x reference)
//
#include <hip/hip_runtime.h>
#include <hip/hip_bf16.h>
#include <cstddef>
#include <cstdint>

constexpr int Tt = 8192;
constexpr int Dd = 768;
constexpr int Nn = 10000;
constexpr int Ww = 32;

typedef __bf16 bf16x8 __attribute__((ext_vector_type(8)));
typedef __bf16 bf16x4 __attribute__((ext_vector_type(4)));
typedef _Float16 half8v __attribute__((ext_vector_type(8)));
typedef _Float16 half4v __attribute__((ext_vector_type(4)));
typedef float f32x4 __attribute__((ext_vector_type(4)));

#define MFMA16(a, b, c) __builtin_amdgcn_mfma_f32_16x16x32_bf16((a), (b), (c), 0, 0, 0)
#define MFMAH(a, b, c) __builtin_amdgcn_mfma_f32_16x16x32_f16((a), (b), (c), 0, 0, 0)

// Simple bf16 converter for fallback tiers.
template <bool LO>
__global__ __launch_bounds__(256) void conv_kernel(const float* __restrict__ src,
                                                   __bf16* __restrict__ h,
                                                   __bf16* __restrict__ l, int n4) {
    const int i = blockIdx.x * 256 + threadIdx.x;
    if (i >= n4) return;
    const float4 v = reinterpret_cast<const float4*>(src)[i];
    bf16x4 oh, ol;
    oh[0] = (__bf16)v.x; oh[1] = (__bf16)v.y; oh[2] = (__bf16)v.z; oh[3] = (__bf16)v.w;
    reinterpret_cast<bf16x4*>(h)[i] = oh;
    if (LO) {
        ol[0] = (__bf16)(v.x - (float)oh[0]);
        ol[1] = (__bf16)(v.y - (float)oh[1]);
        ol[2] = (__bf16)(v.z - (float)oh[2]);
        ol[3] = (__bf16)(v.w - (float)oh[3]);
        reinterpret_cast<bf16x4*>(l)[i] = ol;
    }
}

// ---------------------------------------------------------------------------
// Counting sort kernels — fallback tiers only.
// ---------------------------------------------------------------------------
__global__ __launch_bounds__(256) void zero_kernel(int* __restrict__ p, int n) {
    const int i = blockIdx.x * 256 + threadIdx.x;
    if (i < n) p[i] = 0;
}

__global__ __launch_bounds__(256) void hist_kernel(const int* __restrict__ spans,
                                                   int* __restrict__ hist) {
    const int i = blockIdx.x * 256 + threadIdx.x;
    if (i < Nn) atomicAdd(&hist[spans[2 * i]], 1);
}

__global__ __launch_bounds__(256) void scan_kernel(int* __restrict__ hist) {
    __shared__ int part[256];
    const int t = threadIdx.x;
    int vals[32];
    int sum = 0;
#pragma unroll
    for (int i = 0; i < 32; ++i) { vals[i] = hist[t * 32 + i]; sum += vals[i]; }
    part[t] = sum;
    __syncthreads();
    for (int off = 1; off < 256; off <<= 1) {
        const int v = (t >= off) ? part[t - off] : 0;
        __syncthreads();
        part[t] += v;
        __syncthreads();
    }
    int run = (t == 0) ? 0 : part[t - 1];
#pragma unroll
    for (int i = 0; i < 32; ++i) { const int v = vals[i]; hist[t * 32 + i] = run; run += v; }
}

__global__ __launch_bounds__(256) void scatter_kernel(const int* __restrict__ spans,
                                                      int* __restrict__ offs,
                                                      int* __restrict__ perm) {
    const int i = blockIdx.x * 256 + threadIdx.x;
    if (i < Nn) {
        const int p = atomicAdd(&offs[spans[2 * i]], 1);
        perm[p] = i;
    }
}

// ---------------------------------------------------------------------------
// fp32 vector qproj (fallback tiers). Q = emb @ Wq^T + bq, bf16 hi/lo out.
// ---------------------------------------------------------------------------
template <bool SPLIT>
__global__ __launch_bounds__(256) void qproj_kernel(const float* __restrict__ emb,
                                                    const float* __restrict__ Wq,
                                                    const float* __restrict__ bq,
                                                    __bf16* __restrict__ Qh,
                                                    __bf16* __restrict__ Ql) {
    __shared__ float As[64][32];
    __shared__ float Bs[64][32];
    const int tid = threadIdx.x;
    const int tx = tid & 15;
    const int ty = tid >> 4;
    const int m0 = blockIdx.x * 64;
    const int n0 = blockIdx.y * 64;

    float acc[4][4] = {};

    for (int kc = 0; kc < Dd; kc += 32) {
#pragma unroll
        for (int i = 0; i < 2; ++i) {
            const int f   = tid + i * 256;
            const int row = f >> 3;
            const int c4  = f & 7;
            const int ph  = (c4 + (row >> 2)) & 7;
            *reinterpret_cast<float4*>(&As[row][ph * 4]) =
                *reinterpret_cast<const float4*>(&emb[(size_t)(m0 + row) * Dd + kc + c4 * 4]);
            *reinterpret_cast<float4*>(&Bs[row][ph * 4]) =
                *reinterpret_cast<const float4*>(&Wq[(size_t)(n0 + row) * Dd + kc + c4 * 4]);
        }
        __syncthreads();
#pragma unroll
        for (int d4 = 0; d4 < 8; ++d4) {
            float4 av[4], bv[4];
#pragma unroll
            for (int r = 0; r < 4; ++r)
                av[r] = *reinterpret_cast<const float4*>(&As[ty * 4 + r][((d4 + ty) & 7) * 4]);
#pragma unroll
            for (int c = 0; c < 4; ++c)
                bv[c] = *reinterpret_cast<const float4*>(&Bs[tx * 4 + c][((d4 + tx) & 7) * 4]);
#pragma unroll
            for (int r = 0; r < 4; ++r)
#pragma unroll
                for (int c = 0; c < 4; ++c) {
                    acc[r][c] += av[r].x * bv[c].x;
                    acc[r][c] += av[r].y * bv[c].y;
                    acc[r][c] += av[r].z * bv[c].z;
                    acc[r][c] += av[r].w * bv[c].w;
                }
        }
        __syncthreads();
    }
#pragma unroll
    for (int r = 0; r < 4; ++r) {
        bf16x4 oh, ol;
#pragma unroll
        for (int c = 0; c < 4; ++c) {
            const float v = acc[r][c] + bq[n0 + tx * 4 + c];
            const __bf16 h = (__bf16)v;
            oh[c] = h;
            if (SPLIT) ol[c] = (__bf16)(v - (float)h);
        }
        const size_t off = (size_t)(m0 + ty * 4 + r) * Dd + n0 + tx * 4;
        *reinterpret_cast<bf16x4*>(&Qh[off]) = oh;
        if (SPLIT) *reinterpret_cast<bf16x4*>(&Ql[off]) = ol;
    }
}

// ---------------------------------------------------------------------------
// Fused qproj: reads RAW f32 emb/Wq, converts to f16 in-reg during staging
// (numerically identical to the old conv->Ef/Wf path), computes
// Qf = (f16)emb @ ((f16)Wq)^T + bq with the proven 128x96 MFMA tile, and:
//   - blocks with nt==0 (64 of 512) also store their converted A-tile to Ef
//     (each (row, col-octet) written exactly once -> full Ef for span_attn);
//   - block 512 performs the whole LDS-resident counting sort of spans.
// This removes the conv kernel + 4 sort kernels: main tier = 2 launches.
// ---------------------------------------------------------------------------
__global__ __launch_bounds__(256) void qproj_f16_kernel(const float* __restrict__ emb,
                                                        const float* __restrict__ Wq,
                                                        const float* __restrict__ bq,
                                                        const int* __restrict__ spans,
                                                        _Float16* __restrict__ Ef,
                                                        _Float16* __restrict__ Qf,
                                                        int* __restrict__ perm) {
    __shared__ __align__(16) char smem[33792];  // union: GEMM 28672 B | sort 33792 B

    const int tid  = threadIdx.x;
    const int b    = blockIdx.x;

    if (b == 512) {
        // ---- counting sort of span indices by start, entirely in LDS ----
        int* h    = (int*)smem;            // 8192 bins
        int* part = (int*)(smem + 32768);  // 256 partials
        for (int i = tid; i < 8192; i += 256) h[i] = 0;
        __syncthreads();
        for (int i = tid; i < Nn; i += 256) atomicAdd(&h[spans[2 * i]], 1);
        __syncthreads();
        int vals[32];
        int sum = 0;
#pragma unroll
        for (int i = 0; i < 32; ++i) { vals[i] = h[tid * 32 + i]; sum += vals[i]; }
        part[tid] = sum;
        __syncthreads();
        for (int off = 1; off < 256; off <<= 1) {
            const int v = (tid >= off) ? part[tid - off] : 0;
            __syncthreads();
            part[tid] += v;
            __syncthreads();
        }
        int run = (tid == 0) ? 0 : part[tid - 1];
#pragma unroll
        for (int i = 0; i < 32; ++i) { const int v = vals[i]; h[tid * 32 + i] = run; run += v; }
        __syncthreads();
        for (int i = tid; i < Nn; i += 256) {
            const int p = atomicAdd(&h[spans[2 * i]], 1);
            perm[p] = i;
        }
        return;
    }

    _Float16* As = (_Float16*)smem;            // 128*64 fp16 = 16 KB
    _Float16* Bs = (_Float16*)(smem + 16384);  // 96*64 fp16  = 12 KB

    const int wave = tid >> 6;
    const int lane = tid & 63;

    const int xcd = b & 7;
    const int li  = b >> 3;            // 0..63
    const int mt  = xcd * 8 + (li >> 3);  // 0..63 ; 8 n-tiles per m share XCD
    const int nt  = li & 7;            // 0..7
    const int m0 = mt * 128;
    const int n0 = nt * 96;
    const int wm = (wave & 1) * 64;
    const int wn = (wave >> 1) * 48;
    const int fr = lane & 15;
    const int kg = lane >> 4;

    int ar[4], ao[4];
#pragma unroll
    for (int i = 0; i < 4; ++i) {
        const int s = tid + i * 256;
        ar[i] = s >> 3;
        ao[i] = ((s & 7) ^ (ar[i] & 7)) * 8;
    }
    int br[3], bo[3];
#pragma unroll
    for (int i = 0; i < 3; ++i) {
        const int s = tid + i * 256;
        br[i] = s >> 3;
        bo[i] = ((s & 7) ^ (br[i] & 7)) * 8;
    }

    f32x4 acc[4][3] = {};

    for (int kc = 0; kc < Dd; kc += 64) {
        // Reg-stage raw f32, convert to f16 (identical values to old conv path).
        half8v ra[4], rb[3];
#pragma unroll
        for (int i = 0; i < 4; ++i) {
            const float* src = &emb[(size_t)(m0 + ar[i]) * Dd + kc + ao[i]];
            const float4 lo = *reinterpret_cast<const float4*>(src);
            const float4 hi = *reinterpret_cast<const float4*>(src + 4);
            half8v h;
            h[0] = (_Float16)lo.x; h[1] = (_Float16)lo.y;
            h[2] = (_Float16)lo.z; h[3] = (_Float16)lo.w;
            h[4] = (_Float16)hi.x; h[5] = (_Float16)hi.y;
            h[6] = (_Float16)hi.z; h[7] = (_Float16)hi.w;
            ra[i] = h;
        }
#pragma unroll
        for (int i = 0; i < 3; ++i) {
            const float* src = &Wq[(size_t)(n0 + br[i]) * Dd + kc + bo[i]];
            const float4 lo = *reinterpret_cast<const float4*>(src);
            const float4 hi = *reinterpret_cast<const float4*>(src + 4);
            half8v h;
            h[0] = (_Float16)lo.x; h[1] = (_Float16)lo.y;
            h[2] = (_Float16)lo.z; h[3] = (_Float16)lo.w;
            h[4] = (_Float16)hi.x; h[5] = (_Float16)hi.y;
            h[6] = (_Float16)hi.z; h[7] = (_Float16)hi.w;
            rb[i] = h;
        }
        __syncthreads();  // previous iteration's LDS reads complete
#pragma unroll
        for (int i = 0; i < 4; ++i)
            *reinterpret_cast<half8v*>(&As[(tid + i * 256) * 8]) = ra[i];
#pragma unroll
        for (int i = 0; i < 3; ++i)
            *reinterpret_cast<half8v*>(&Bs[(tid + i * 256) * 8]) = rb[i];
        // One n-tile per m-tile persists the converted A-tile -> Ef.
        if (nt == 0) {
#pragma unroll
            for (int i = 0; i < 4; ++i)
                *reinterpret_cast<half8v*>(&Ef[(size_t)(m0 + ar[i]) * Dd + kc + ao[i]]) = ra[i];
        }
        __syncthreads();  // writes visible

#pragma unroll
        for (int step = 0; step < 2; ++step) {
            const int g = kg + 4 * step;  // global octet within 64-col chunk
            half8v a[4], bb[3];
#pragma unroll
            for (int r = 0; r < 4; ++r) {
                const int R = wm + r * 16 + fr;
                a[r] = *reinterpret_cast<const half8v*>(&As[R * 64 + (g ^ (R & 7)) * 8]);
            }
#pragma unroll
            for (int c = 0; c < 3; ++c) {
                const int R = wn + c * 16 + fr;
                bb[c] = *reinterpret_cast<const half8v*>(&Bs[R * 64 + (g ^ (R & 7)) * 8]);
            }
#pragma unroll
            for (int r = 0; r < 4; ++r)
#pragma unroll
                for (int c = 0; c < 3; ++c)
                    acc[r][c] = MFMAH(a[r], bb[c], acc[r][c]);
        }
    }

    // Epilogue: C/D layout col=lane&15, row=(lane>>4)*4+reg.
#pragma unroll
    for (int c = 0; c < 3; ++c) {
        const int ocol = n0 + wn + c * 16 + fr;
        const float bqv = bq[ocol];
#pragma unroll
        for (int r = 0; r < 4; ++r)
#pragma unroll
            for (int j = 0; j < 4; ++j) {
                const int orow = m0 + wm + r * 16 + kg * 4 + j;
                Qf[(size_t)orow * Dd + ocol] = (_Float16)(acc[r][c][j] + bqv);
            }
    }
}

// ---------------------------------------------------------------------------
// Span attention (proven, 52 us): fp16, window-shared LDS, single-buffered
// sync staging, ST=136; softmax + col sums in registers. Byte-identical to
// the best-measured configuration.
// ---------------------------------------------------------------------------
__global__ __launch_bounds__(256) void span_attn_win_kernel(const _Float16* __restrict__ Ef,
                                                            const int* __restrict__ spans,
                                                            const _Float16* __restrict__ Qf,
                                                            const int* __restrict__ perm,
                                                            float* __restrict__ out) {
    constexpr int WR = 48, CH = 128, ST = 136, NCH = Dd / CH;
    __shared__ __align__(16) _Float16 Qs[WR * ST];
    __shared__ __align__(16) _Float16 Es[WR * ST];

    const int tid  = threadIdx.x;
    const int wave = tid >> 6;
    const int lane = tid & 63;

    const int b     = blockIdx.x;
    const int bp    = (b & 7) * 313 + (b >> 3);
    const int slot0 = bp * 4;
    const int slot  = slot0 + wave;
    const bool active = slot < Nn;

    int s0 = perm[slot0 < Nn ? slot0 : (Nn - 1)];
    if ((unsigned)s0 >= (unsigned)Nn) s0 = 0;
    int s = active ? perm[slot] : s0;
    if ((unsigned)s >= (unsigned)Nn) s = 0;

    const int w0    = spans[2 * s0];
    const int start = spans[2 * s];
    const int L     = spans[2 * s + 1] - start + 1;  // 1..32
    const bool big  = L > 16;
    const int sl    = start - w0;
    const bool inwin = active && sl >= 0 && sl <= (WR - 32);

    const int row = lane & 15;  // A-frag m; C-col k
    const int kq  = lane >> 4;

    const size_t gq = (size_t)(start + row) * Dd + kq * 8;  // fallback base

    f32x4 acc00 = {0.f, 0.f, 0.f, 0.f};
    f32x4 acc01 = {0.f, 0.f, 0.f, 0.f};
    f32x4 acc10 = {0.f, 0.f, 0.f, 0.f};
    f32x4 acc11 = {0.f, 0.f, 0.f, 0.f};

    for (int c = 0; c < NCH; ++c) {
        const int c0 = c * CH;
        __syncthreads();  // previous chunk's LDS reads complete
#pragma unroll
        for (int i = 0; i < 3; ++i) {
            const int seg = tid + i * 256;  // 768 segs: 48 rows x 16 col-segs
            const int r  = seg >> 4;
            const int cs = seg & 15;
            const int gr = w0 + r < Tt ? w0 + r : Tt - 1;  // clamp (pad rows unused)
            const size_t ga = (size_t)gr * Dd + c0 + cs * 8;
            *reinterpret_cast<half8v*>(&Qs[r * ST + cs * 8]) =
                *reinterpret_cast<const half8v*>(&Qf[ga]);
            *reinterpret_cast<half8v*>(&Es[r * ST + cs * 8]) =
                *reinterpret_cast<const half8v*>(&Ef[ga]);
        }
        __syncthreads();

        if (inwin) {
            const int ab = (sl + row) * ST + kq * 8;
#pragma unroll
            for (int j = 0; j < 4; ++j) {
                const int o = j * 32;
                const half8v a0 = *reinterpret_cast<const half8v*>(&Qs[ab + o]);
                const half8v b0 = *reinterpret_cast<const half8v*>(&Es[ab + o]);
                acc00 = MFMAH(a0, b0, acc00);
                if (big) {
                    const half8v a1 = *reinterpret_cast<const half8v*>(&Qs[ab + 16 * ST + o]);
                    const half8v b1 = *reinterpret_cast<const half8v*>(&Es[ab + 16 * ST + o]);
                    acc01 = MFMAH(a0, b1, acc01);
                    acc10 = MFMAH(a1, b0, acc10);
                    acc11 = MFMAH(a1, b1, acc11);
                }
            }
        } else if (active) {
            // rare: span exceeds window — direct global fragment loads
#pragma unroll
            for (int j = 0; j < 4; ++j) {
                const int o = c0 + j * 32;
                const half8v a0 = *reinterpret_cast<const half8v*>(&Qf[gq + o]);
                const half8v b0 = *reinterpret_cast<const half8v*>(&Ef[gq + o]);
                acc00 = MFMAH(a0, b0, acc00);
                if (big) {
                    const half8v a1 = *reinterpret_cast<const half8v*>(&Qf[gq + 16 * Dd + o]);
                    const half8v b1 = *reinterpret_cast<const half8v*>(&Ef[gq + 16 * Dd + o]);
                    acc01 = MFMAH(a0, b1, acc01);
                    acc10 = MFMAH(a1, b0, acc10);
                    acc11 = MFMAH(a1, b1, acc11);
                }
            }
        }
    }

    // ---- In-register softmax + column sums ----
    const float NEG = -1e30f;
    const bool kv0 = row < L;
    const bool kv1 = (16 + row) < L;
    float cA, cB;
    {
        float w00[4], w01[4], w10[4], w11[4];
#pragma unroll
        for (int r = 0; r < 4; ++r) {
            float m = kv0 ? acc00[r] : NEG;
            if (big) m = fmaxf(m, kv1 ? acc01[r] : NEG);
#pragma unroll
            for (int st = 1; st <= 8; st <<= 1) m = fmaxf(m, __shfl_xor(m, st));
            const float e0 = kv0 ? __expf(acc00[r] - m) : 0.f;
            const float e1 = (big && kv1) ? __expf(acc01[r] - m) : 0.f;
            float sum = e0 + e1;
#pragma unroll
            for (int st = 1; st <= 8; st <<= 1) sum += __shfl_xor(sum, st);
            const float inv = 1.f / sum;
            const bool qv = (kq * 4 + r) < L;
            w00[r] = qv ? e0 * inv : 0.f;
            w01[r] = qv ? e1 * inv : 0.f;
            if (big) {
                float mh = kv0 ? acc10[r] : NEG;
                mh = fmaxf(mh, kv1 ? acc11[r] : NEG);
#pragma unroll
                for (int st = 1; st <= 8; st <<= 1) mh = fmaxf(mh, __shfl_xor(mh, st));
                const float f0 = kv0 ? __expf(acc10[r] - mh) : 0.f;
                const float f1 = kv1 ? __expf(acc11[r] - mh) : 0.f;
                float sh = f0 + f1;
#pragma unroll
                for (int st = 1; st <= 8; st <<= 1) sh += __shfl_xor(sh, st);
                const float invh = 1.f / sh;
                const bool qvh = (16 + kq * 4 + r) < L;
                w10[r] = qvh ? f0 * invh : 0.f;
                w11[r] = qvh ? f1 * invh : 0.f;
            }
        }
        float pa = w00[0] + w00[1] + w00[2] + w00[3];
        float pb = 0.f;
        if (big) {
            pa += w10[0] + w10[1] + w10[2] + w10[3];
            pb = w01[0] + w01[1] + w01[2] + w01[3] +
                 w11[0] + w11[1] + w11[2] + w11[3];
        }
        pa += __shfl_xor(pa, 16);
        pa += __shfl_xor(pa, 32);
        if (big) {
            pb += __shfl_xor(pb, 16);
            pb += __shfl_xor(pb, 32);
        }
        cA = pa;
        cB = pb;
    }

    // ---- Output: out[s][d] = sum_k c_k * E[start+k][d], fp16 reads ----
    if (active) {
        f32x4 o[3] = {};
        const int KP = (L + 3) & ~3;
        const _Float16* ebase = Ef + (size_t)start * Dd + lane * 4;
        for (int k = 0; k < KP; k += 4) {
            float cv[4];
            half4v ev[4][3];
#pragma unroll
            for (int j = 0; j < 4; ++j) {
                const int kk = k + j;
                cv[j] = (kk < 16) ? __shfl(cA, kk) : __shfl(cB, kk - 16);
#pragma unroll
                for (int i = 0; i < 3; ++i)
                    ev[j][i] = *reinterpret_cast<const half4v*>(ebase + (size_t)kk * Dd + i * 256);
            }
#pragma unroll
            for (int j = 0; j < 4; ++j)
#pragma unroll
                for (int i = 0; i < 3; ++i) {
                    o[i][0] += cv[j] * (float)ev[j][i][0];
                    o[i][1] += cv[j] * (float)ev[j][i][1];
                    o[i][2] += cv[j] * (float)ev[j][i][2];
                    o[i][3] += cv[j] * (float)ev[j][i][3];
                }
        }
#pragma unroll
        for (int i = 0; i < 3; ++i)
            *reinterpret_cast<f32x4*>(&out[(size_t)s * Dd + i * 256 + lane * 4]) = o[i];
    }
}

// ---------------------------------------------------------------------------
// Round-5 bf16 global span kernel (proven) — fallback tiers only.
// ---------------------------------------------------------------------------
template <bool SPLIT, bool SORTED>
__global__ __launch_bounds__(256) void span_attn_g_kernel(const __bf16* __restrict__ Eb,
                                                          const int* __restrict__ spans,
                                                          const __bf16* __restrict__ Qh,
                                                          const __bf16* __restrict__ Ql,
                                                          const int* __restrict__ perm,
                                                          float* __restrict__ out) {
    const int wave = threadIdx.x >> 6;
    const int lane = threadIdx.x & 63;

    int s;
    bool active;
    if (SORTED) {
        const int b    = blockIdx.x;
        const int bp   = (b & 7) * 313 + (b >> 3);
        const int slot = bp * 4 + wave;
        active = slot < Nn;
        int sv = active ? perm[slot] : 0;
        if ((unsigned)sv >= (unsigned)Nn) sv = 0;
        s = sv;
    } else {
        s = blockIdx.x * 4 + wave;
        active = true;
    }

    const int start = spans[2 * s];
    const int L     = spans[2 * s + 1] - start + 1;
    const bool big  = L > 16;

    const int row = lane & 15;
    const int kq  = lane >> 4;

    const size_t rbase = (size_t)(start + row) * Dd + kq * 8;
    const __bf16* qh0 = Qh + rbase;
    const __bf16* eb0 = Eb + rbase;
    const __bf16* ql0 = SPLIT ? (Ql + rbase) : nullptr;

    f32x4 acc00 = {0.f, 0.f, 0.f, 0.f};
    f32x4 acc01 = {0.f, 0.f, 0.f, 0.f};
    f32x4 acc10 = {0.f, 0.f, 0.f, 0.f};
    f32x4 acc11 = {0.f, 0.f, 0.f, 0.f};

    if (!big) {
        for (int kc = 0; kc < Dd; kc += 128) {
            bf16x8 A[4], B[4], AL[4];
#pragma unroll
            for (int j = 0; j < 4; ++j) {
                const int o = kc + j * 32;
                A[j] = *reinterpret_cast<const bf16x8*>(qh0 + o);
                B[j] = *reinterpret_cast<const bf16x8*>(eb0 + o);
                if (SPLIT) AL[j] = *reinterpret_cast<const bf16x8*>(ql0 + o);
            }
#pragma unroll
            for (int j = 0; j < 4; ++j) {
                acc00 = MFMA16(A[j], B[j], acc00);
                if (SPLIT) acc00 = MFMA16(AL[j], B[j], acc00);
            }
        }
    } else {
        for (int kc = 0; kc < Dd; kc += 64) {
            bf16x8 A0[2], A1[2], B0[2], B1[2], AL0[2], AL1[2];
#pragma unroll
            for (int j = 0; j < 2; ++j) {
                const int o = kc + j * 32;
                A0[j] = *reinterpret_cast<const bf16x8*>(qh0 + o);
                A1[j] = *reinterpret_cast<const bf16x8*>(qh0 + 16 * Dd + o);
                B0[j] = *reinterpret_cast<const bf16x8*>(eb0 + o);
                B1[j] = *reinterpret_cast<const bf16x8*>(eb0 + 16 * Dd + o);
                if (SPLIT) {
                    AL0[j] = *reinterpret_cast<const bf16x8*>(ql0 + o);
                    AL1[j] = *reinterpret_cast<const bf16x8*>(ql0 + 16 * Dd + o);
                }
            }
#pragma unroll
            for (int j = 0; j < 2; ++j) {
                acc00 = MFMA16(A0[j], B0[j], acc00);
                acc01 = MFMA16(A0[j], B1[j], acc01);
                acc10 = MFMA16(A1[j], B0[j], acc10);
                acc11 = MFMA16(A1[j], B1[j], acc11);
                if (SPLIT) {
                    acc00 = MFMA16(AL0[j], B0[j], acc00);
                    acc01 = MFMA16(AL0[j], B1[j], acc01);
                    acc10 = MFMA16(AL1[j], B0[j], acc10);
                    acc11 = MFMA16(AL1[j], B1[j], acc11);
                }
            }
        }
    }

    const float NEG = -1e30f;
    const bool kv0 = row < L;
    const bool kv1 = (16 + row) < L;
    float cA, cB;
    {
        float w00[4], w01[4], w10[4], w11[4];
#pragma unroll
        for (int r = 0; r < 4; ++r) {
            float m = kv0 ? acc00[r] : NEG;
            if (big) m = fmaxf(m, kv1 ? acc01[r] : NEG);
#pragma unroll
            for (int st = 1; st <= 8; st <<= 1) m = fmaxf(m, __shfl_xor(m, st));
            const float e0 = kv0 ? __expf(acc00[r] - m) : 0.f;
            const float e1 = (big && kv1) ? __expf(acc01[r] - m) : 0.f;
            float sum = e0 + e1;
#pragma unroll
            for (int st = 1; st <= 8; st <<= 1) sum += __shfl_xor(sum, st);
            const float inv = 1.f / sum;
            const bool qv = (kq * 4 + r) < L;
            w00[r] = qv ? e0 * inv : 0.f;
            w01[r] = qv ? e1 * inv : 0.f;
            if (big) {
                float mh = kv0 ? acc10[r] : NEG;
                mh = fmaxf(mh, kv1 ? acc11[r] : NEG);
#pragma unroll
                for (int st = 1; st <= 8; st <<= 1) mh = fmaxf(mh, __shfl_xor(mh, st));
                const float f0 = kv0 ? __expf(acc10[r] - mh) : 0.f;
                const float f1 = kv1 ? __expf(acc11[r] - mh) : 0.f;
                float sh = f0 + f1;
#pragma unroll
                for (int st = 1; st <= 8; st <<= 1) sh += __shfl_xor(sh, st);
                const float invh = 1.f / sh;
                const bool qvh = (16 + kq * 4 + r) < L;
                w10[r] = qvh ? f0 * invh : 0.f;
                w11[r] = qvh ? f1 * invh : 0.f;
            }
        }
        float pa = w00[0] + w00[1] + w00[2] + w00[3];
        float pb = 0.f;
        if (big) {
            pa += w10[0] + w10[1] + w10[2] + w10[3];
            pb = w01[0] + w01[1] + w01[2] + w01[3] +
                 w11[0] + w11[1] + w11[2] + w11[3];
        }
        pa += __shfl_xor(pa, 16);
        pa += __shfl_xor(pa, 32);
        if (big) {
            pb += __shfl_xor(pb, 16);
            pb += __shfl_xor(pb, 32);
        }
        cA = pa;
        cB = pb;
    }

    if (active) {
        f32x4 o[3] = {};
        const int KP = (L + 3) & ~3;
        const __bf16* ebase = Eb + (size_t)start * Dd + lane * 4;
        for (int k = 0; k < KP; k += 4) {
            float cv[4];
            bf16x4 ev[4][3];
#pragma unroll
            for (int j = 0; j < 4; ++j) {
                const int kk = k + j;
                cv[j] = (kk < 16) ? __shfl(cA, kk) : __shfl(cB, kk - 16);
#pragma unroll
                for (int i = 0; i < 3; ++i)
                    ev[j][i] = *reinterpret_cast<const bf16x4*>(ebase + (size_t)kk * Dd + i * 256);
            }
#pragma unroll
            for (int j = 0; j < 4; ++j)
#pragma unroll
                for (int i = 0; i < 3; ++i) {
                    o[i][0] += cv[j] * (float)ev[j][i][0];
                    o[i][1] += cv[j] * (float)ev[j][i][1];
                    o[i][2] += cv[j] * (float)ev[j][i][2];
                    o[i][3] += cv[j] * (float)ev[j][i][3];
                }
        }
#pragma unroll
        for (int i = 0; i < 3; ++i)
            *reinterpret_cast<f32x4*>(&out[(size_t)s * Dd + i * 256 + lane * 4]) = o[i];
    }
}

// ---------------------------------------------------------------------------
extern "C" void kernel_launch(void* const* d_in, const int* in_sizes, int n_in,
                              void* d_out, int out_size, void* d_ws, size_t ws_size,
                              hipStream_t stream) {
    const float* emb   = (const float*)d_in[0];
    const int*   spans = (const int*)d_in[1];
    const float* Wq    = (const float*)d_in[2];
    const float* bq    = (const float*)d_in[3];
    float*       out   = (float*)d_out;

    const size_t TD = (size_t)Tt * Dd;
    const size_t DD = (size_t)Dd * Dd;
    const size_t intBytes = (size_t)(8192 + 10016) * sizeof(int);
    auto align16 = [](size_t x) { return (x + 15) & ~(size_t)15; };

    const size_t needMain = align16((2 * TD + DD) * 2) + intBytes;  // ~26.6 MB
    const size_t needB = align16(3 * TD * 2) + intBytes;
    const size_t needC = 3 * TD * 2;

    if (ws_size >= needMain) {
        char* base = (char*)d_ws;
        _Float16* Qf = (_Float16*)base;
        _Float16* Ef = (_Float16*)(base + TD * 2);
        int* hist = (int*)(base + align16((2 * TD + DD) * 2));
        int* perm = hist + 8192;

        // K1: fused conv + qproj (blocks 0..511) + hidden counting sort (block 512).
        qproj_f16_kernel<<<513, 256, 0, stream>>>(emb, Wq, bq, spans, Ef, Qf, perm);
        // K2: span attention.
        span_attn_win_kernel<<<2504, 256, 0, stream>>>(Ef, spans, Qf, perm, out);
    } else if (ws_size >= needB) {
        __bf16* w = (__bf16*)d_ws;
        __bf16* Qh = w;
        __bf16* Ql = w + TD;
        __bf16* Eh = w + 2 * TD;
        int* hist = (int*)((char*)d_ws + align16(3 * TD * 2));
        int* perm = hist + 8192;

        conv_kernel<false><<<(int)(TD / 4 / 256), 256, 0, stream>>>(emb, Eh, nullptr, (int)(TD / 4));
        zero_kernel<<<32, 256, 0, stream>>>(hist, 8192);
        hist_kernel<<<40, 256, 0, stream>>>(spans, hist);
        scan_kernel<<<1, 256, 0, stream>>>(hist);
        scatter_kernel<<<40, 256, 0, stream>>>(spans, hist, perm);
        qproj_kernel<true><<<dim3(Tt / 64, Dd / 64), 256, 0, stream>>>(emb, Wq, bq, Qh, Ql);
        span_attn_g_kernel<true, true><<<2504, 256, 0, stream>>>(Eh, spans, Qh, Ql, perm, out);
    } else if (ws_size >= needC) {
        __bf16* w = (__bf16*)d_ws;
        __bf16* Qh = w;
        __bf16* Ql = w + TD;
        __bf16* Eh = w + 2 * TD;
        conv_kernel<false><<<(int)(TD / 4 / 256), 256, 0, stream>>>(emb, Eh, nullptr, (int)(TD / 4));
        qproj_kernel<true><<<dim3(Tt / 64, Dd / 64), 256, 0, stream>>>(emb, Wq, bq, Qh, Ql);
        span_attn_g_kernel<true, false><<<2500, 256, 0, stream>>>(Eh, spans, Qh, Ql, nullptr, out);
    } else {
        __bf16* w = (__bf16*)d_ws;
        __bf16* Qh = w;
        __bf16* Eh = w + TD;
        conv_kernel<false><<<(int)(TD / 4 / 256), 256, 0, stream>>>(emb, Eh, nullptr, (int)(TD / 4));
        qproj_kernel<false><<<dim3(Tt / 64, Dd / 64), 256, 0, stream>>>(emb, Wq, bq, Qh, nullptr);
        span_attn_g_kernel<false, false><<<2500, 256, 0, stream>>>(Eh, spans, Qh, nullptr, nullptr, out);
    }
}

// Round 9
// 158.634 us; speedup vs baseline: 1.0154x; 1.0154x over previous
//
#include <hip/hip_runtime.h>
#include <hip/hip_bf16.h>
#include <cstddef>
#include <cstdint>

constexpr int Tt = 8192;
constexpr int Dd = 768;
constexpr int Nn = 10000;
constexpr int Ww = 32;

typedef __bf16 bf16x8 __attribute__((ext_vector_type(8)));
typedef __bf16 bf16x4 __attribute__((ext_vector_type(4)));
typedef _Float16 half8v __attribute__((ext_vector_type(8)));
typedef _Float16 half4v __attribute__((ext_vector_type(4)));
typedef float f32x4 __attribute__((ext_vector_type(4)));

#define MFMA16(a, b, c) __builtin_amdgcn_mfma_f32_16x16x32_bf16((a), (b), (c), 0, 0, 0)
#define MFMAH(a, b, c) __builtin_amdgcn_mfma_f32_16x16x32_f16((a), (b), (c), 0, 0, 0)

// Simple bf16 converter for fallback tiers.
template <bool LO>
__global__ __launch_bounds__(256) void conv_kernel(const float* __restrict__ src,
                                                   __bf16* __restrict__ h,
                                                   __bf16* __restrict__ l, int n4) {
    const int i = blockIdx.x * 256 + threadIdx.x;
    if (i >= n4) return;
    const float4 v = reinterpret_cast<const float4*>(src)[i];
    bf16x4 oh, ol;
    oh[0] = (__bf16)v.x; oh[1] = (__bf16)v.y; oh[2] = (__bf16)v.z; oh[3] = (__bf16)v.w;
    reinterpret_cast<bf16x4*>(h)[i] = oh;
    if (LO) {
        ol[0] = (__bf16)(v.x - (float)oh[0]);
        ol[1] = (__bf16)(v.y - (float)oh[1]);
        ol[2] = (__bf16)(v.z - (float)oh[2]);
        ol[3] = (__bf16)(v.w - (float)oh[3]);
        reinterpret_cast<bf16x4*>(l)[i] = ol;
    }
}

// ---------------------------------------------------------------------------
// Counting sort kernels — fallback tiers only.
// ---------------------------------------------------------------------------
__global__ __launch_bounds__(256) void zero_kernel(int* __restrict__ p, int n) {
    const int i = blockIdx.x * 256 + threadIdx.x;
    if (i < n) p[i] = 0;
}

__global__ __launch_bounds__(256) void hist_kernel(const int* __restrict__ spans,
                                                   int* __restrict__ hist) {
    const int i = blockIdx.x * 256 + threadIdx.x;
    if (i < Nn) atomicAdd(&hist[spans[2 * i]], 1);
}

__global__ __launch_bounds__(256) void scan_kernel(int* __restrict__ hist) {
    __shared__ int part[256];
    const int t = threadIdx.x;
    int vals[32];
    int sum = 0;
#pragma unroll
    for (int i = 0; i < 32; ++i) { vals[i] = hist[t * 32 + i]; sum += vals[i]; }
    part[t] = sum;
    __syncthreads();
    for (int off = 1; off < 256; off <<= 1) {
        const int v = (t >= off) ? part[t - off] : 0;
        __syncthreads();
        part[t] += v;
        __syncthreads();
    }
    int run = (t == 0) ? 0 : part[t - 1];
#pragma unroll
    for (int i = 0; i < 32; ++i) { const int v = vals[i]; hist[t * 32 + i] = run; run += v; }
}

__global__ __launch_bounds__(256) void scatter_kernel(const int* __restrict__ spans,
                                                      int* __restrict__ offs,
                                                      int* __restrict__ perm) {
    const int i = blockIdx.x * 256 + threadIdx.x;
    if (i < Nn) {
        const int p = atomicAdd(&offs[spans[2 * i]], 1);
        perm[p] = i;
    }
}

// ---------------------------------------------------------------------------
// fp32 vector qproj (fallback tiers). Q = emb @ Wq^T + bq, bf16 hi/lo out.
// ---------------------------------------------------------------------------
template <bool SPLIT>
__global__ __launch_bounds__(256) void qproj_kernel(const float* __restrict__ emb,
                                                    const float* __restrict__ Wq,
                                                    const float* __restrict__ bq,
                                                    __bf16* __restrict__ Qh,
                                                    __bf16* __restrict__ Ql) {
    __shared__ float As[64][32];
    __shared__ float Bs[64][32];
    const int tid = threadIdx.x;
    const int tx = tid & 15;
    const int ty = tid >> 4;
    const int m0 = blockIdx.x * 64;
    const int n0 = blockIdx.y * 64;

    float acc[4][4] = {};

    for (int kc = 0; kc < Dd; kc += 32) {
#pragma unroll
        for (int i = 0; i < 2; ++i) {
            const int f   = tid + i * 256;
            const int row = f >> 3;
            const int c4  = f & 7;
            const int ph  = (c4 + (row >> 2)) & 7;
            *reinterpret_cast<float4*>(&As[row][ph * 4]) =
                *reinterpret_cast<const float4*>(&emb[(size_t)(m0 + row) * Dd + kc + c4 * 4]);
            *reinterpret_cast<float4*>(&Bs[row][ph * 4]) =
                *reinterpret_cast<const float4*>(&Wq[(size_t)(n0 + row) * Dd + kc + c4 * 4]);
        }
        __syncthreads();
#pragma unroll
        for (int d4 = 0; d4 < 8; ++d4) {
            float4 av[4], bv[4];
#pragma unroll
            for (int r = 0; r < 4; ++r)
                av[r] = *reinterpret_cast<const float4*>(&As[ty * 4 + r][((d4 + ty) & 7) * 4]);
#pragma unroll
            for (int c = 0; c < 4; ++c)
                bv[c] = *reinterpret_cast<const float4*>(&Bs[tx * 4 + c][((d4 + tx) & 7) * 4]);
#pragma unroll
            for (int r = 0; r < 4; ++r)
#pragma unroll
                for (int c = 0; c < 4; ++c) {
                    acc[r][c] += av[r].x * bv[c].x;
                    acc[r][c] += av[r].y * bv[c].y;
                    acc[r][c] += av[r].z * bv[c].z;
                    acc[r][c] += av[r].w * bv[c].w;
                }
        }
        __syncthreads();
    }
#pragma unroll
    for (int r = 0; r < 4; ++r) {
        bf16x4 oh, ol;
#pragma unroll
        for (int c = 0; c < 4; ++c) {
            const float v = acc[r][c] + bq[n0 + tx * 4 + c];
            const __bf16 h = (__bf16)v;
            oh[c] = h;
            if (SPLIT) ol[c] = (__bf16)(v - (float)h);
        }
        const size_t off = (size_t)(m0 + ty * 4 + r) * Dd + n0 + tx * 4;
        *reinterpret_cast<bf16x4*>(&Qh[off]) = oh;
        if (SPLIT) *reinterpret_cast<bf16x4*>(&Ql[off]) = ol;
    }
}

// ---------------------------------------------------------------------------
// Fused qproj v2 (software-pipelined): reads RAW f32 emb/Wq. The f32 segments
// for K-step kc+64 are loaded into registers RIGHT AFTER the second barrier,
// BEFORE the 24 MFMAs of step kc — their first use (the f32->f16 convert at
// the write site) is a full compute phase + barrier later, so L2 latency is
// covered. Registers are free: occupancy is grid-limited (513 blocks = 2/CU).
//   - blocks with nt==0 also persist their converted A-tile to Ef;
//   - block 512 performs the whole LDS-resident counting sort of spans.
// Main tier = 2 launches.
// ---------------------------------------------------------------------------
__global__ __launch_bounds__(256) void qproj_f16_kernel(const float* __restrict__ emb,
                                                        const float* __restrict__ Wq,
                                                        const float* __restrict__ bq,
                                                        const int* __restrict__ spans,
                                                        _Float16* __restrict__ Ef,
                                                        _Float16* __restrict__ Qf,
                                                        int* __restrict__ perm) {
    __shared__ __align__(16) char smem[33792];  // union: GEMM 28672 B | sort 33792 B

    const int tid  = threadIdx.x;
    const int b    = blockIdx.x;

    if (b == 512) {
        // ---- counting sort of span indices by start, entirely in LDS ----
        int* h    = (int*)smem;            // 8192 bins
        int* part = (int*)(smem + 32768);  // 256 partials
        for (int i = tid; i < 8192; i += 256) h[i] = 0;
        __syncthreads();
        for (int i = tid; i < Nn; i += 256) atomicAdd(&h[spans[2 * i]], 1);
        __syncthreads();
        int vals[32];
        int sum = 0;
#pragma unroll
        for (int i = 0; i < 32; ++i) { vals[i] = h[tid * 32 + i]; sum += vals[i]; }
        part[tid] = sum;
        __syncthreads();
        for (int off = 1; off < 256; off <<= 1) {
            const int v = (tid >= off) ? part[tid - off] : 0;
            __syncthreads();
            part[tid] += v;
            __syncthreads();
        }
        int run = (tid == 0) ? 0 : part[tid - 1];
#pragma unroll
        for (int i = 0; i < 32; ++i) { const int v = vals[i]; h[tid * 32 + i] = run; run += v; }
        __syncthreads();
        for (int i = tid; i < Nn; i += 256) {
            const int p = atomicAdd(&h[spans[2 * i]], 1);
            perm[p] = i;
        }
        return;
    }

    _Float16* As = (_Float16*)smem;            // 128*64 fp16 = 16 KB
    _Float16* Bs = (_Float16*)(smem + 16384);  // 96*64 fp16  = 12 KB

    const int wave = tid >> 6;
    const int lane = tid & 63;

    const int xcd = b & 7;
    const int li  = b >> 3;            // 0..63
    const int mt  = xcd * 8 + (li >> 3);  // 0..63 ; 8 n-tiles per m share XCD
    const int nt  = li & 7;            // 0..7
    const int m0 = mt * 128;
    const int n0 = nt * 96;
    const int wm = (wave & 1) * 64;
    const int wn = (wave >> 1) * 48;
    const int fr = lane & 15;
    const int kg = lane >> 4;

    int ar[4], ao[4];
#pragma unroll
    for (int i = 0; i < 4; ++i) {
        const int s = tid + i * 256;
        ar[i] = s >> 3;
        ao[i] = ((s & 7) ^ (ar[i] & 7)) * 8;
    }
    int br[3], bo[3];
#pragma unroll
    for (int i = 0; i < 3; ++i) {
        const int s = tid + i * 256;
        br[i] = s >> 3;
        bo[i] = ((s & 7) ^ (br[i] & 7)) * 8;
    }

    f32x4 acc[4][3] = {};

    // Prologue: load K-step 0's raw f32 segments into registers.
    f32x4 fa[4][2], fb[3][2];
#pragma unroll
    for (int i = 0; i < 4; ++i) {
        const float* src = &emb[(size_t)(m0 + ar[i]) * Dd + ao[i]];
        fa[i][0] = *reinterpret_cast<const f32x4*>(src);
        fa[i][1] = *reinterpret_cast<const f32x4*>(src + 4);
    }
#pragma unroll
    for (int i = 0; i < 3; ++i) {
        const float* src = &Wq[(size_t)(n0 + br[i]) * Dd + bo[i]];
        fb[i][0] = *reinterpret_cast<const f32x4*>(src);
        fb[i][1] = *reinterpret_cast<const f32x4*>(src + 4);
    }

    for (int kc = 0; kc < Dd; kc += 64) {
        __syncthreads();  // previous iteration's LDS reads complete
        // Convert staged f32 -> f16, write LDS (+ persist A-tile to Ef once).
#pragma unroll
        for (int i = 0; i < 4; ++i) {
            half8v h;
            h[0] = (_Float16)fa[i][0][0]; h[1] = (_Float16)fa[i][0][1];
            h[2] = (_Float16)fa[i][0][2]; h[3] = (_Float16)fa[i][0][3];
            h[4] = (_Float16)fa[i][1][0]; h[5] = (_Float16)fa[i][1][1];
            h[6] = (_Float16)fa[i][1][2]; h[7] = (_Float16)fa[i][1][3];
            *reinterpret_cast<half8v*>(&As[(tid + i * 256) * 8]) = h;
            if (nt == 0)
                *reinterpret_cast<half8v*>(&Ef[(size_t)(m0 + ar[i]) * Dd + kc + ao[i]]) = h;
        }
#pragma unroll
        for (int i = 0; i < 3; ++i) {
            half8v h;
            h[0] = (_Float16)fb[i][0][0]; h[1] = (_Float16)fb[i][0][1];
            h[2] = (_Float16)fb[i][0][2]; h[3] = (_Float16)fb[i][0][3];
            h[4] = (_Float16)fb[i][1][0]; h[5] = (_Float16)fb[i][1][1];
            h[6] = (_Float16)fb[i][1][2]; h[7] = (_Float16)fb[i][1][3];
            *reinterpret_cast<half8v*>(&Bs[(tid + i * 256) * 8]) = h;
        }
        __syncthreads();  // writes visible

        // Issue NEXT K-step's loads before compute: latency hides under MFMAs.
        if (kc + 64 < Dd) {
#pragma unroll
            for (int i = 0; i < 4; ++i) {
                const float* src = &emb[(size_t)(m0 + ar[i]) * Dd + kc + 64 + ao[i]];
                fa[i][0] = *reinterpret_cast<const f32x4*>(src);
                fa[i][1] = *reinterpret_cast<const f32x4*>(src + 4);
            }
#pragma unroll
            for (int i = 0; i < 3; ++i) {
                const float* src = &Wq[(size_t)(n0 + br[i]) * Dd + kc + 64 + bo[i]];
                fb[i][0] = *reinterpret_cast<const f32x4*>(src);
                fb[i][1] = *reinterpret_cast<const f32x4*>(src + 4);
            }
        }

#pragma unroll
        for (int step = 0; step < 2; ++step) {
            const int g = kg + 4 * step;  // global octet within 64-col chunk
            half8v a[4], bb[3];
#pragma unroll
            for (int r = 0; r < 4; ++r) {
                const int R = wm + r * 16 + fr;
                a[r] = *reinterpret_cast<const half8v*>(&As[R * 64 + (g ^ (R & 7)) * 8]);
            }
#pragma unroll
            for (int c = 0; c < 3; ++c) {
                const int R = wn + c * 16 + fr;
                bb[c] = *reinterpret_cast<const half8v*>(&Bs[R * 64 + (g ^ (R & 7)) * 8]);
            }
#pragma unroll
            for (int r = 0; r < 4; ++r)
#pragma unroll
                for (int c = 0; c < 3; ++c)
                    acc[r][c] = MFMAH(a[r], bb[c], acc[r][c]);
        }
    }

    // Epilogue: C/D layout col=lane&15, row=(lane>>4)*4+reg.
#pragma unroll
    for (int c = 0; c < 3; ++c) {
        const int ocol = n0 + wn + c * 16 + fr;
        const float bqv = bq[ocol];
#pragma unroll
        for (int r = 0; r < 4; ++r)
#pragma unroll
            for (int j = 0; j < 4; ++j) {
                const int orow = m0 + wm + r * 16 + kg * 4 + j;
                Qf[(size_t)orow * Dd + ocol] = (_Float16)(acc[r][c][j] + bqv);
            }
    }
}

// ---------------------------------------------------------------------------
// Span attention (proven, 52 us): fp16, window-shared LDS, single-buffered
// sync staging, ST=136; softmax + col sums in registers. Byte-identical to
// the best-measured configuration.
// ---------------------------------------------------------------------------
__global__ __launch_bounds__(256) void span_attn_win_kernel(const _Float16* __restrict__ Ef,
                                                            const int* __restrict__ spans,
                                                            const _Float16* __restrict__ Qf,
                                                            const int* __restrict__ perm,
                                                            float* __restrict__ out) {
    constexpr int WR = 48, CH = 128, ST = 136, NCH = Dd / CH;
    __shared__ __align__(16) _Float16 Qs[WR * ST];
    __shared__ __align__(16) _Float16 Es[WR * ST];

    const int tid  = threadIdx.x;
    const int wave = tid >> 6;
    const int lane = tid & 63;

    const int b     = blockIdx.x;
    const int bp    = (b & 7) * 313 + (b >> 3);
    const int slot0 = bp * 4;
    const int slot  = slot0 + wave;
    const bool active = slot < Nn;

    int s0 = perm[slot0 < Nn ? slot0 : (Nn - 1)];
    if ((unsigned)s0 >= (unsigned)Nn) s0 = 0;
    int s = active ? perm[slot] : s0;
    if ((unsigned)s >= (unsigned)Nn) s = 0;

    const int w0    = spans[2 * s0];
    const int start = spans[2 * s];
    const int L     = spans[2 * s + 1] - start + 1;  // 1..32
    const bool big  = L > 16;
    const int sl    = start - w0;
    const bool inwin = active && sl >= 0 && sl <= (WR - 32);

    const int row = lane & 15;  // A-frag m; C-col k
    const int kq  = lane >> 4;

    const size_t gq = (size_t)(start + row) * Dd + kq * 8;  // fallback base

    f32x4 acc00 = {0.f, 0.f, 0.f, 0.f};
    f32x4 acc01 = {0.f, 0.f, 0.f, 0.f};
    f32x4 acc10 = {0.f, 0.f, 0.f, 0.f};
    f32x4 acc11 = {0.f, 0.f, 0.f, 0.f};

    for (int c = 0; c < NCH; ++c) {
        const int c0 = c * CH;
        __syncthreads();  // previous chunk's LDS reads complete
#pragma unroll
        for (int i = 0; i < 3; ++i) {
            const int seg = tid + i * 256;  // 768 segs: 48 rows x 16 col-segs
            const int r  = seg >> 4;
            const int cs = seg & 15;
            const int gr = w0 + r < Tt ? w0 + r : Tt - 1;  // clamp (pad rows unused)
            const size_t ga = (size_t)gr * Dd + c0 + cs * 8;
            *reinterpret_cast<half8v*>(&Qs[r * ST + cs * 8]) =
                *reinterpret_cast<const half8v*>(&Qf[ga]);
            *reinterpret_cast<half8v*>(&Es[r * ST + cs * 8]) =
                *reinterpret_cast<const half8v*>(&Ef[ga]);
        }
        __syncthreads();

        if (inwin) {
            const int ab = (sl + row) * ST + kq * 8;
#pragma unroll
            for (int j = 0; j < 4; ++j) {
                const int o = j * 32;
                const half8v a0 = *reinterpret_cast<const half8v*>(&Qs[ab + o]);
                const half8v b0 = *reinterpret_cast<const half8v*>(&Es[ab + o]);
                acc00 = MFMAH(a0, b0, acc00);
                if (big) {
                    const half8v a1 = *reinterpret_cast<const half8v*>(&Qs[ab + 16 * ST + o]);
                    const half8v b1 = *reinterpret_cast<const half8v*>(&Es[ab + 16 * ST + o]);
                    acc01 = MFMAH(a0, b1, acc01);
                    acc10 = MFMAH(a1, b0, acc10);
                    acc11 = MFMAH(a1, b1, acc11);
                }
            }
        } else if (active) {
            // rare: span exceeds window — direct global fragment loads
#pragma unroll
            for (int j = 0; j < 4; ++j) {
                const int o = c0 + j * 32;
                const half8v a0 = *reinterpret_cast<const half8v*>(&Qf[gq + o]);
                const half8v b0 = *reinterpret_cast<const half8v*>(&Ef[gq + o]);
                acc00 = MFMAH(a0, b0, acc00);
                if (big) {
                    const half8v a1 = *reinterpret_cast<const half8v*>(&Qf[gq + 16 * Dd + o]);
                    const half8v b1 = *reinterpret_cast<const half8v*>(&Ef[gq + 16 * Dd + o]);
                    acc01 = MFMAH(a0, b1, acc01);
                    acc10 = MFMAH(a1, b0, acc10);
                    acc11 = MFMAH(a1, b1, acc11);
                }
            }
        }
    }

    // ---- In-register softmax + column sums ----
    const float NEG = -1e30f;
    const bool kv0 = row < L;
    const bool kv1 = (16 + row) < L;
    float cA, cB;
    {
        float w00[4], w01[4], w10[4], w11[4];
#pragma unroll
        for (int r = 0; r < 4; ++r) {
            float m = kv0 ? acc00[r] : NEG;
            if (big) m = fmaxf(m, kv1 ? acc01[r] : NEG);
#pragma unroll
            for (int st = 1; st <= 8; st <<= 1) m = fmaxf(m, __shfl_xor(m, st));
            const float e0 = kv0 ? __expf(acc00[r] - m) : 0.f;
            const float e1 = (big && kv1) ? __expf(acc01[r] - m) : 0.f;
            float sum = e0 + e1;
#pragma unroll
            for (int st = 1; st <= 8; st <<= 1) sum += __shfl_xor(sum, st);
            const float inv = 1.f / sum;
            const bool qv = (kq * 4 + r) < L;
            w00[r] = qv ? e0 * inv : 0.f;
            w01[r] = qv ? e1 * inv : 0.f;
            if (big) {
                float mh = kv0 ? acc10[r] : NEG;
                mh = fmaxf(mh, kv1 ? acc11[r] : NEG);
#pragma unroll
                for (int st = 1; st <= 8; st <<= 1) mh = fmaxf(mh, __shfl_xor(mh, st));
                const float f0 = kv0 ? __expf(acc10[r] - mh) : 0.f;
                const float f1 = kv1 ? __expf(acc11[r] - mh) : 0.f;
                float sh = f0 + f1;
#pragma unroll
                for (int st = 1; st <= 8; st <<= 1) sh += __shfl_xor(sh, st);
                const float invh = 1.f / sh;
                const bool qvh = (16 + kq * 4 + r) < L;
                w10[r] = qvh ? f0 * invh : 0.f;
                w11[r] = qvh ? f1 * invh : 0.f;
            }
        }
        float pa = w00[0] + w00[1] + w00[2] + w00[3];
        float pb = 0.f;
        if (big) {
            pa += w10[0] + w10[1] + w10[2] + w10[3];
            pb = w01[0] + w01[1] + w01[2] + w01[3] +
                 w11[0] + w11[1] + w11[2] + w11[3];
        }
        pa += __shfl_xor(pa, 16);
        pa += __shfl_xor(pa, 32);
        if (big) {
            pb += __shfl_xor(pb, 16);
            pb += __shfl_xor(pb, 32);
        }
        cA = pa;
        cB = pb;
    }

    // ---- Output: out[s][d] = sum_k c_k * E[start+k][d], fp16 reads ----
    if (active) {
        f32x4 o[3] = {};
        const int KP = (L + 3) & ~3;
        const _Float16* ebase = Ef + (size_t)start * Dd + lane * 4;
        for (int k = 0; k < KP; k += 4) {
            float cv[4];
            half4v ev[4][3];
#pragma unroll
            for (int j = 0; j < 4; ++j) {
                const int kk = k + j;
                cv[j] = (kk < 16) ? __shfl(cA, kk) : __shfl(cB, kk - 16);
#pragma unroll
                for (int i = 0; i < 3; ++i)
                    ev[j][i] = *reinterpret_cast<const half4v*>(ebase + (size_t)kk * Dd + i * 256);
            }
#pragma unroll
            for (int j = 0; j < 4; ++j)
#pragma unroll
                for (int i = 0; i < 3; ++i) {
                    o[i][0] += cv[j] * (float)ev[j][i][0];
                    o[i][1] += cv[j] * (float)ev[j][i][1];
                    o[i][2] += cv[j] * (float)ev[j][i][2];
                    o[i][3] += cv[j] * (float)ev[j][i][3];
                }
        }
#pragma unroll
        for (int i = 0; i < 3; ++i)
            *reinterpret_cast<f32x4*>(&out[(size_t)s * Dd + i * 256 + lane * 4]) = o[i];
    }
}

// ---------------------------------------------------------------------------
// Round-5 bf16 global span kernel (proven) — fallback tiers only.
// ---------------------------------------------------------------------------
template <bool SPLIT, bool SORTED>
__global__ __launch_bounds__(256) void span_attn_g_kernel(const __bf16* __restrict__ Eb,
                                                          const int* __restrict__ spans,
                                                          const __bf16* __restrict__ Qh,
                                                          const __bf16* __restrict__ Ql,
                                                          const int* __restrict__ perm,
                                                          float* __restrict__ out) {
    const int wave = threadIdx.x >> 6;
    const int lane = threadIdx.x & 63;

    int s;
    bool active;
    if (SORTED) {
        const int b    = blockIdx.x;
        const int bp   = (b & 7) * 313 + (b >> 3);
        const int slot = bp * 4 + wave;
        active = slot < Nn;
        int sv = active ? perm[slot] : 0;
        if ((unsigned)sv >= (unsigned)Nn) sv = 0;
        s = sv;
    } else {
        s = blockIdx.x * 4 + wave;
        active = true;
    }

    const int start = spans[2 * s];
    const int L     = spans[2 * s + 1] - start + 1;
    const bool big  = L > 16;

    const int row = lane & 15;
    const int kq  = lane >> 4;

    const size_t rbase = (size_t)(start + row) * Dd + kq * 8;
    const __bf16* qh0 = Qh + rbase;
    const __bf16* eb0 = Eb + rbase;
    const __bf16* ql0 = SPLIT ? (Ql + rbase) : nullptr;

    f32x4 acc00 = {0.f, 0.f, 0.f, 0.f};
    f32x4 acc01 = {0.f, 0.f, 0.f, 0.f};
    f32x4 acc10 = {0.f, 0.f, 0.f, 0.f};
    f32x4 acc11 = {0.f, 0.f, 0.f, 0.f};

    if (!big) {
        for (int kc = 0; kc < Dd; kc += 128) {
            bf16x8 A[4], B[4], AL[4];
#pragma unroll
            for (int j = 0; j < 4; ++j) {
                const int o = kc + j * 32;
                A[j] = *reinterpret_cast<const bf16x8*>(qh0 + o);
                B[j] = *reinterpret_cast<const bf16x8*>(eb0 + o);
                if (SPLIT) AL[j] = *reinterpret_cast<const bf16x8*>(ql0 + o);
            }
#pragma unroll
            for (int j = 0; j < 4; ++j) {
                acc00 = MFMA16(A[j], B[j], acc00);
                if (SPLIT) acc00 = MFMA16(AL[j], B[j], acc00);
            }
        }
    } else {
        for (int kc = 0; kc < Dd; kc += 64) {
            bf16x8 A0[2], A1[2], B0[2], B1[2], AL0[2], AL1[2];
#pragma unroll
            for (int j = 0; j < 2; ++j) {
                const int o = kc + j * 32;
                A0[j] = *reinterpret_cast<const bf16x8*>(qh0 + o);
                A1[j] = *reinterpret_cast<const bf16x8*>(qh0 + 16 * Dd + o);
                B0[j] = *reinterpret_cast<const bf16x8*>(eb0 + o);
                B1[j] = *reinterpret_cast<const bf16x8*>(eb0 + 16 * Dd + o);
                if (SPLIT) {
                    AL0[j] = *reinterpret_cast<const bf16x8*>(ql0 + o);
                    AL1[j] = *reinterpret_cast<const bf16x8*>(ql0 + 16 * Dd + o);
                }
            }
#pragma unroll
            for (int j = 0; j < 2; ++j) {
                acc00 = MFMA16(A0[j], B0[j], acc00);
                acc01 = MFMA16(A0[j], B1[j], acc01);
                acc10 = MFMA16(A1[j], B0[j], acc10);
                acc11 = MFMA16(A1[j], B1[j], acc11);
                if (SPLIT) {
                    acc00 = MFMA16(AL0[j], B0[j], acc00);
                    acc01 = MFMA16(AL0[j], B1[j], acc01);
                    acc10 = MFMA16(AL1[j], B0[j], acc10);
                    acc11 = MFMA16(AL1[j], B1[j], acc11);
                }
            }
        }
    }

    const float NEG = -1e30f;
    const bool kv0 = row < L;
    const bool kv1 = (16 + row) < L;
    float cA, cB;
    {
        float w00[4], w01[4], w10[4], w11[4];
#pragma unroll
        for (int r = 0; r < 4; ++r) {
            float m = kv0 ? acc00[r] : NEG;
            if (big) m = fmaxf(m, kv1 ? acc01[r] : NEG);
#pragma unroll
            for (int st = 1; st <= 8; st <<= 1) m = fmaxf(m, __shfl_xor(m, st));
            const float e0 = kv0 ? __expf(acc00[r] - m) : 0.f;
            const float e1 = (big && kv1) ? __expf(acc01[r] - m) : 0.f;
            float sum = e0 + e1;
#pragma unroll
            for (int st = 1; st <= 8; st <<= 1) sum += __shfl_xor(sum, st);
            const float inv = 1.f / sum;
            const bool qv = (kq * 4 + r) < L;
            w00[r] = qv ? e0 * inv : 0.f;
            w01[r] = qv ? e1 * inv : 0.f;
            if (big) {
                float mh = kv0 ? acc10[r] : NEG;
                mh = fmaxf(mh, kv1 ? acc11[r] : NEG);
#pragma unroll
                for (int st = 1; st <= 8; st <<= 1) mh = fmaxf(mh, __shfl_xor(mh, st));
                const float f0 = kv0 ? __expf(acc10[r] - mh) : 0.f;
                const float f1 = kv1 ? __expf(acc11[r] - mh) : 0.f;
                float sh = f0 + f1;
#pragma unroll
                for (int st = 1; st <= 8; st <<= 1) sh += __shfl_xor(sh, st);
                const float invh = 1.f / sh;
                const bool qvh = (16 + kq * 4 + r) < L;
                w10[r] = qvh ? f0 * invh : 0.f;
                w11[r] = qvh ? f1 * invh : 0.f;
            }
        }
        float pa = w00[0] + w00[1] + w00[2] + w00[3];
        float pb = 0.f;
        if (big) {
            pa += w10[0] + w10[1] + w10[2] + w10[3];
            pb = w01[0] + w01[1] + w01[2] + w01[3] +
                 w11[0] + w11[1] + w11[2] + w11[3];
        }
        pa += __shfl_xor(pa, 16);
        pa += __shfl_xor(pa, 32);
        if (big) {
            pb += __shfl_xor(pb, 16);
            pb += __shfl_xor(pb, 32);
        }
        cA = pa;
        cB = pb;
    }

    if (active) {
        f32x4 o[3] = {};
        const int KP = (L + 3) & ~3;
        const __bf16* ebase = Eb + (size_t)start * Dd + lane * 4;
        for (int k = 0; k < KP; k += 4) {
            float cv[4];
            bf16x4 ev[4][3];
#pragma unroll
            for (int j = 0; j < 4; ++j) {
                const int kk = k + j;
                cv[j] = (kk < 16) ? __shfl(cA, kk) : __shfl(cB, kk - 16);
#pragma unroll
                for (int i = 0; i < 3; ++i)
                    ev[j][i] = *reinterpret_cast<const bf16x4*>(ebase + (size_t)kk * Dd + i * 256);
            }
#pragma unroll
            for (int j = 0; j < 4; ++j)
#pragma unroll
                for (int i = 0; i < 3; ++i) {
                    o[i][0] += cv[j] * (float)ev[j][i][0];
                    o[i][1] += cv[j] * (float)ev[j][i][1];
                    o[i][2] += cv[j] * (float)ev[j][i][2];
                    o[i][3] += cv[j] * (float)ev[j][i][3];
                }
        }
#pragma unroll
        for (int i = 0; i < 3; ++i)
            *reinterpret_cast<f32x4*>(&out[(size_t)s * Dd + i * 256 + lane * 4]) = o[i];
    }
}

// ---------------------------------------------------------------------------
extern "C" void kernel_launch(void* const* d_in, const int* in_sizes, int n_in,
                              void* d_out, int out_size, void* d_ws, size_t ws_size,
                              hipStream_t stream) {
    const float* emb   = (const float*)d_in[0];
    const int*   spans = (const int*)d_in[1];
    const float* Wq    = (const float*)d_in[2];
    const float* bq    = (const float*)d_in[3];
    float*       out   = (float*)d_out;

    const size_t TD = (size_t)Tt * Dd;
    const size_t DD = (size_t)Dd * Dd;
    const size_t intBytes = (size_t)(8192 + 10016) * sizeof(int);
    auto align16 = [](size_t x) { return (x + 15) & ~(size_t)15; };

    const size_t needMain = align16((2 * TD + DD) * 2) + intBytes;  // ~26.6 MB
    const size_t needB = align16(3 * TD * 2) + intBytes;
    const size_t needC = 3 * TD * 2;

    if (ws_size >= needMain) {
        char* base = (char*)d_ws;
        _Float16* Qf = (_Float16*)base;
        _Float16* Ef = (_Float16*)(base + TD * 2);
        int* hist = (int*)(base + align16((2 * TD + DD) * 2));
        int* perm = hist + 8192;

        // K1: fused conv + qproj (blocks 0..511, software-pipelined staging)
        //     + hidden counting sort (block 512).
        qproj_f16_kernel<<<513, 256, 0, stream>>>(emb, Wq, bq, spans, Ef, Qf, perm);
        // K2: span attention.
        span_attn_win_kernel<<<2504, 256, 0, stream>>>(Ef, spans, Qf, perm, out);
    } else if (ws_size >= needB) {
        __bf16* w = (__bf16*)d_ws;
        __bf16* Qh = w;
        __bf16* Ql = w + TD;
        __bf16* Eh = w + 2 * TD;
        int* hist = (int*)((char*)d_ws + align16(3 * TD * 2));
        int* perm = hist + 8192;

        conv_kernel<false><<<(int)(TD / 4 / 256), 256, 0, stream>>>(emb, Eh, nullptr, (int)(TD / 4));
        zero_kernel<<<32, 256, 0, stream>>>(hist, 8192);
        hist_kernel<<<40, 256, 0, stream>>>(spans, hist);
        scan_kernel<<<1, 256, 0, stream>>>(hist);
        scatter_kernel<<<40, 256, 0, stream>>>(spans, hist, perm);
        qproj_kernel<true><<<dim3(Tt / 64, Dd / 64), 256, 0, stream>>>(emb, Wq, bq, Qh, Ql);
        span_attn_g_kernel<true, true><<<2504, 256, 0, stream>>>(Eh, spans, Qh, Ql, perm, out);
    } else if (ws_size >= needC) {
        __bf16* w = (__bf16*)d_ws;
        __bf16* Qh = w;
        __bf16* Ql = w + TD;
        __bf16* Eh = w + 2 * TD;
        conv_kernel<false><<<(int)(TD / 4 / 256), 256, 0, stream>>>(emb, Eh, nullptr, (int)(TD / 4));
        qproj_kernel<true><<<dim3(Tt / 64, Dd / 64), 256, 0, stream>>>(emb, Wq, bq, Qh, Ql);
        span_attn_g_kernel<true, false><<<2500, 256, 0, stream>>>(Eh, spans, Qh, Ql, nullptr, out);
    } else {
        __bf16* w = (__bf16*)d_ws;
        __bf16* Qh = w;
        __bf16* Eh = w + TD;
        conv_kernel<false><<<(int)(TD / 4 / 256), 256, 0, stream>>>(emb, Eh, nullptr, (int)(TD / 4));
        qproj_kernel<false><<<dim3(Tt / 64, Dd / 64), 256, 0, stream>>>(emb, Wq, bq, Qh, nullptr);
        span_attn_g_kernel<false, false><<<2500, 256, 0, stream>>>(Eh, spans, Qh, nullptr, nullptr, out);
    }
}

// Round 10
// 157.243 us; speedup vs baseline: 1.0243x; 1.0088x over previous
//
#include <hip/hip_runtime.h>
#include <hip/hip_bf16.h>
#include <cstddef>
#include <cstdint>

constexpr int Tt = 8192;
constexpr int Dd = 768;
constexpr int Nn = 10000;
constexpr int Ww = 32;

typedef __bf16 bf16x8 __attribute__((ext_vector_type(8)));
typedef __bf16 bf16x4 __attribute__((ext_vector_type(4)));
typedef _Float16 half8v __attribute__((ext_vector_type(8)));
typedef _Float16 half4v __attribute__((ext_vector_type(4)));
typedef float f32x4 __attribute__((ext_vector_type(4)));

#define MFMA16(a, b, c) __builtin_amdgcn_mfma_f32_16x16x32_bf16((a), (b), (c), 0, 0, 0)
#define MFMAH(a, b, c) __builtin_amdgcn_mfma_f32_16x16x32_f16((a), (b), (c), 0, 0, 0)

// ---------------------------------------------------------------------------
// Converter: emb -> Ef (fp16), Wq -> Wf (fp16).
// ---------------------------------------------------------------------------
__global__ __launch_bounds__(256) void conv_f16_kernel(const float* __restrict__ emb,
                                                       const float* __restrict__ Wq,
                                                       _Float16* __restrict__ Ef,
                                                       _Float16* __restrict__ Wf) {
    const int nE = (Tt * Dd) / 4;
    const int nW = (Dd * Dd) / 4;
    const int i = blockIdx.x * 256 + threadIdx.x;
    if (i < nE) {
        const float4 v = reinterpret_cast<const float4*>(emb)[i];
        half4v o;
        o[0] = (_Float16)v.x; o[1] = (_Float16)v.y;
        o[2] = (_Float16)v.z; o[3] = (_Float16)v.w;
        reinterpret_cast<half4v*>(Ef)[i] = o;
    } else {
        const int j = i - nE;
        if (j < nW) {
            const float4 v = reinterpret_cast<const float4*>(Wq)[j];
            half4v o;
            o[0] = (_Float16)v.x; o[1] = (_Float16)v.y;
            o[2] = (_Float16)v.z; o[3] = (_Float16)v.w;
            reinterpret_cast<half4v*>(Wf)[j] = o;
        }
    }
}

// Simple bf16 converter for fallback tiers.
template <bool LO>
__global__ __launch_bounds__(256) void conv_kernel(const float* __restrict__ src,
                                                   __bf16* __restrict__ h,
                                                   __bf16* __restrict__ l, int n4) {
    const int i = blockIdx.x * 256 + threadIdx.x;
    if (i >= n4) return;
    const float4 v = reinterpret_cast<const float4*>(src)[i];
    bf16x4 oh, ol;
    oh[0] = (__bf16)v.x; oh[1] = (__bf16)v.y; oh[2] = (__bf16)v.z; oh[3] = (__bf16)v.w;
    reinterpret_cast<bf16x4*>(h)[i] = oh;
    if (LO) {
        ol[0] = (__bf16)(v.x - (float)oh[0]);
        ol[1] = (__bf16)(v.y - (float)oh[1]);
        ol[2] = (__bf16)(v.z - (float)oh[2]);
        ol[3] = (__bf16)(v.w - (float)oh[3]);
        reinterpret_cast<bf16x4*>(l)[i] = ol;
    }
}

// ---------------------------------------------------------------------------
// Counting sort of span indices by start. Rebuilt fully every call.
// ---------------------------------------------------------------------------
__global__ __launch_bounds__(256) void zero_kernel(int* __restrict__ p, int n) {
    const int i = blockIdx.x * 256 + threadIdx.x;
    if (i < n) p[i] = 0;
}

__global__ __launch_bounds__(256) void hist_kernel(const int* __restrict__ spans,
                                                   int* __restrict__ hist) {
    const int i = blockIdx.x * 256 + threadIdx.x;
    if (i < Nn) atomicAdd(&hist[spans[2 * i]], 1);
}

__global__ __launch_bounds__(256) void scan_kernel(int* __restrict__ hist) {
    __shared__ int part[256];
    const int t = threadIdx.x;
    int vals[32];
    int sum = 0;
#pragma unroll
    for (int i = 0; i < 32; ++i) { vals[i] = hist[t * 32 + i]; sum += vals[i]; }
    part[t] = sum;
    __syncthreads();
    for (int off = 1; off < 256; off <<= 1) {
        const int v = (t >= off) ? part[t - off] : 0;
        __syncthreads();
        part[t] += v;
        __syncthreads();
    }
    int run = (t == 0) ? 0 : part[t - 1];
#pragma unroll
    for (int i = 0; i < 32; ++i) { const int v = vals[i]; hist[t * 32 + i] = run; run += v; }
}

__global__ __launch_bounds__(256) void scatter_kernel(const int* __restrict__ spans,
                                                      int* __restrict__ offs,
                                                      int* __restrict__ perm) {
    const int i = blockIdx.x * 256 + threadIdx.x;
    if (i < Nn) {
        const int p = atomicAdd(&offs[spans[2 * i]], 1);
        perm[p] = i;
    }
}

// ---------------------------------------------------------------------------
// fp32 vector qproj (fallback tiers). Q = emb @ Wq^T + bq, bf16 hi/lo out.
// ---------------------------------------------------------------------------
template <bool SPLIT>
__global__ __launch_bounds__(256) void qproj_kernel(const float* __restrict__ emb,
                                                    const float* __restrict__ Wq,
                                                    const float* __restrict__ bq,
                                                    __bf16* __restrict__ Qh,
                                                    __bf16* __restrict__ Ql) {
    __shared__ float As[64][32];
    __shared__ float Bs[64][32];
    const int tid = threadIdx.x;
    const int tx = tid & 15;
    const int ty = tid >> 4;
    const int m0 = blockIdx.x * 64;
    const int n0 = blockIdx.y * 64;

    float acc[4][4] = {};

    for (int kc = 0; kc < Dd; kc += 32) {
#pragma unroll
        for (int i = 0; i < 2; ++i) {
            const int f   = tid + i * 256;
            const int row = f >> 3;
            const int c4  = f & 7;
            const int ph  = (c4 + (row >> 2)) & 7;
            *reinterpret_cast<float4*>(&As[row][ph * 4]) =
                *reinterpret_cast<const float4*>(&emb[(size_t)(m0 + row) * Dd + kc + c4 * 4]);
            *reinterpret_cast<float4*>(&Bs[row][ph * 4]) =
                *reinterpret_cast<const float4*>(&Wq[(size_t)(n0 + row) * Dd + kc + c4 * 4]);
        }
        __syncthreads();
#pragma unroll
        for (int d4 = 0; d4 < 8; ++d4) {
            float4 av[4], bv[4];
#pragma unroll
            for (int r = 0; r < 4; ++r)
                av[r] = *reinterpret_cast<const float4*>(&As[ty * 4 + r][((d4 + ty) & 7) * 4]);
#pragma unroll
            for (int c = 0; c < 4; ++c)
                bv[c] = *reinterpret_cast<const float4*>(&Bs[tx * 4 + c][((d4 + tx) & 7) * 4]);
#pragma unroll
            for (int r = 0; r < 4; ++r)
#pragma unroll
                for (int c = 0; c < 4; ++c) {
                    acc[r][c] += av[r].x * bv[c].x;
                    acc[r][c] += av[r].y * bv[c].y;
                    acc[r][c] += av[r].z * bv[c].z;
                    acc[r][c] += av[r].w * bv[c].w;
                }
        }
        __syncthreads();
    }
#pragma unroll
    for (int r = 0; r < 4; ++r) {
        bf16x4 oh, ol;
#pragma unroll
        for (int c = 0; c < 4; ++c) {
            const float v = acc[r][c] + bq[n0 + tx * 4 + c];
            const __bf16 h = (__bf16)v;
            oh[c] = h;
            if (SPLIT) ol[c] = (__bf16)(v - (float)h);
        }
        const size_t off = (size_t)(m0 + ty * 4 + r) * Dd + n0 + tx * 4;
        *reinterpret_cast<bf16x4*>(&Qh[off]) = oh;
        if (SPLIT) *reinterpret_cast<bf16x4*>(&Ql[off]) = ol;
    }
}

// ---------------------------------------------------------------------------
// qproj fp16 v3: Qf = Ef @ Wf^T + bq. SAME staging/XOR-octet/MFMA structure
// as the proven R0 kernel, but tile 128x48 with grid 1024 (vs 128x96 / 512):
// 4 blocks/CU resident (16 waves/CU) instead of 2 — double the TLP for this
// latency-bound kernel (R7/R9 counters: VALUBusy <=8%, occupancy 8-19%).
// LDS 22 KB (A 16K + B 6K); 4 waves each own a 32x48 sub-tile (acc[2][3]).
// Per-XCD A panel = 8 m-tiles x 128 rows x 1.5 KB = 1.5 MB (fits 4 MB L2).
// ---------------------------------------------------------------------------
__global__ __launch_bounds__(256) void qproj_f16_kernel(const _Float16* __restrict__ Ef,
                                                        const _Float16* __restrict__ Wf,
                                                        const float* __restrict__ bq,
                                                        _Float16* __restrict__ Qf) {
    __shared__ __align__(16) _Float16 As[128 * 64];  // 16 KB
    __shared__ __align__(16) _Float16 Bs[48 * 64];   // 6 KB

    const int tid  = threadIdx.x;
    const int wave = tid >> 6;
    const int lane = tid & 63;

    const int b   = blockIdx.x;           // 0..1023
    const int xcd = b & 7;
    const int li  = b >> 3;               // 0..127
    const int mt  = xcd * 8 + (li >> 4);  // 0..63 ; 16 n-tiles per m share XCD
    const int nt  = li & 15;              // 0..15
    const int m0 = mt * 128;
    const int n0 = nt * 48;
    const int wm = wave * 32;             // wave owns rows wm..wm+31, all 48 cols
    const int fr = lane & 15;
    const int kg = lane >> 4;

    // Staging geometry. A: 1024 segs (4/thread). B: 384 segs (1.5/thread,
    // second segment predicated on tid<128). Seg s -> row r = s>>3, LDS
    // octet s&7 holding GLOBAL octet (s&7)^(r&7) (involution).
    int ar[4], ao[4];
#pragma unroll
    for (int i = 0; i < 4; ++i) {
        const int s = tid + i * 256;
        ar[i] = s >> 3;
        ao[i] = ((s & 7) ^ (ar[i] & 7)) * 8;
    }
    const int br0 = tid >> 3;
    const int bo0 = ((tid & 7) ^ (br0 & 7)) * 8;
    const int s1  = tid + 256;
    const int br1 = s1 >> 3;
    const int bo1 = ((s1 & 7) ^ (br1 & 7)) * 8;
    const bool hasB1 = tid < 128;

    f32x4 acc[2][3] = {};

    for (int kc = 0; kc < Dd; kc += 64) {
        half8v ra[4], rb0, rb1 = {};
#pragma unroll
        for (int i = 0; i < 4; ++i)
            ra[i] = *reinterpret_cast<const half8v*>(&Ef[(size_t)(m0 + ar[i]) * Dd + kc + ao[i]]);
        rb0 = *reinterpret_cast<const half8v*>(&Wf[(size_t)(n0 + br0) * Dd + kc + bo0]);
        if (hasB1)
            rb1 = *reinterpret_cast<const half8v*>(&Wf[(size_t)(n0 + br1) * Dd + kc + bo1]);
        __syncthreads();  // previous iteration's LDS reads complete
#pragma unroll
        for (int i = 0; i < 4; ++i)
            *reinterpret_cast<half8v*>(&As[(tid + i * 256) * 8]) = ra[i];
        *reinterpret_cast<half8v*>(&Bs[tid * 8]) = rb0;
        if (hasB1)
            *reinterpret_cast<half8v*>(&Bs[(tid + 256) * 8]) = rb1;
        __syncthreads();  // writes visible

#pragma unroll
        for (int step = 0; step < 2; ++step) {
            const int g = kg + 4 * step;  // global octet within 64-col chunk
            half8v a[2], bb[3];
#pragma unroll
            for (int r = 0; r < 2; ++r) {
                const int R = wm + r * 16 + fr;
                a[r] = *reinterpret_cast<const half8v*>(&As[R * 64 + (g ^ (R & 7)) * 8]);
            }
#pragma unroll
            for (int c = 0; c < 3; ++c) {
                const int R = c * 16 + fr;
                bb[c] = *reinterpret_cast<const half8v*>(&Bs[R * 64 + (g ^ (R & 7)) * 8]);
            }
#pragma unroll
            for (int r = 0; r < 2; ++r)
#pragma unroll
                for (int c = 0; c < 3; ++c)
                    acc[r][c] = MFMAH(a[r], bb[c], acc[r][c]);
        }
    }

    // Epilogue: C/D layout col=lane&15, row=(lane>>4)*4+reg.
#pragma unroll
    for (int c = 0; c < 3; ++c) {
        const int ocol = n0 + c * 16 + fr;
        const float bqv = bq[ocol];
#pragma unroll
        for (int r = 0; r < 2; ++r)
#pragma unroll
            for (int j = 0; j < 4; ++j) {
                const int orow = m0 + wm + r * 16 + kg * 4 + j;
                Qf[(size_t)orow * Dd + ocol] = (_Float16)(acc[r][c][j] + bqv);
            }
    }
}

// ---------------------------------------------------------------------------
// Span attention (proven, 52 us): fp16, window-shared LDS, single-buffered
// sync staging, ST=136; softmax + col sums in registers. Byte-identical to
// the best-measured configuration.
// ---------------------------------------------------------------------------
__global__ __launch_bounds__(256) void span_attn_win_kernel(const _Float16* __restrict__ Ef,
                                                            const int* __restrict__ spans,
                                                            const _Float16* __restrict__ Qf,
                                                            const int* __restrict__ perm,
                                                            float* __restrict__ out) {
    constexpr int WR = 48, CH = 128, ST = 136, NCH = Dd / CH;
    __shared__ __align__(16) _Float16 Qs[WR * ST];
    __shared__ __align__(16) _Float16 Es[WR * ST];

    const int tid  = threadIdx.x;
    const int wave = tid >> 6;
    const int lane = tid & 63;

    const int b     = blockIdx.x;
    const int bp    = (b & 7) * 313 + (b >> 3);
    const int slot0 = bp * 4;
    const int slot  = slot0 + wave;
    const bool active = slot < Nn;

    int s0 = perm[slot0 < Nn ? slot0 : (Nn - 1)];
    if ((unsigned)s0 >= (unsigned)Nn) s0 = 0;
    int s = active ? perm[slot] : s0;
    if ((unsigned)s >= (unsigned)Nn) s = 0;

    const int w0    = spans[2 * s0];
    const int start = spans[2 * s];
    const int L     = spans[2 * s + 1] - start + 1;  // 1..32
    const bool big  = L > 16;
    const int sl    = start - w0;
    const bool inwin = active && sl >= 0 && sl <= (WR - 32);

    const int row = lane & 15;  // A-frag m; C-col k
    const int kq  = lane >> 4;

    const size_t gq = (size_t)(start + row) * Dd + kq * 8;  // fallback base

    f32x4 acc00 = {0.f, 0.f, 0.f, 0.f};
    f32x4 acc01 = {0.f, 0.f, 0.f, 0.f};
    f32x4 acc10 = {0.f, 0.f, 0.f, 0.f};
    f32x4 acc11 = {0.f, 0.f, 0.f, 0.f};

    for (int c = 0; c < NCH; ++c) {
        const int c0 = c * CH;
        __syncthreads();  // previous chunk's LDS reads complete
#pragma unroll
        for (int i = 0; i < 3; ++i) {
            const int seg = tid + i * 256;  // 768 segs: 48 rows x 16 col-segs
            const int r  = seg >> 4;
            const int cs = seg & 15;
            const int gr = w0 + r < Tt ? w0 + r : Tt - 1;  // clamp (pad rows unused)
            const size_t ga = (size_t)gr * Dd + c0 + cs * 8;
            *reinterpret_cast<half8v*>(&Qs[r * ST + cs * 8]) =
                *reinterpret_cast<const half8v*>(&Qf[ga]);
            *reinterpret_cast<half8v*>(&Es[r * ST + cs * 8]) =
                *reinterpret_cast<const half8v*>(&Ef[ga]);
        }
        __syncthreads();

        if (inwin) {
            const int ab = (sl + row) * ST + kq * 8;
#pragma unroll
            for (int j = 0; j < 4; ++j) {
                const int o = j * 32;
                const half8v a0 = *reinterpret_cast<const half8v*>(&Qs[ab + o]);
                const half8v b0 = *reinterpret_cast<const half8v*>(&Es[ab + o]);
                acc00 = MFMAH(a0, b0, acc00);
                if (big) {
                    const half8v a1 = *reinterpret_cast<const half8v*>(&Qs[ab + 16 * ST + o]);
                    const half8v b1 = *reinterpret_cast<const half8v*>(&Es[ab + 16 * ST + o]);
                    acc01 = MFMAH(a0, b1, acc01);
                    acc10 = MFMAH(a1, b0, acc10);
                    acc11 = MFMAH(a1, b1, acc11);
                }
            }
        } else if (active) {
            // rare: span exceeds window — direct global fragment loads
#pragma unroll
            for (int j = 0; j < 4; ++j) {
                const int o = c0 + j * 32;
                const half8v a0 = *reinterpret_cast<const half8v*>(&Qf[gq + o]);
                const half8v b0 = *reinterpret_cast<const half8v*>(&Ef[gq + o]);
                acc00 = MFMAH(a0, b0, acc00);
                if (big) {
                    const half8v a1 = *reinterpret_cast<const half8v*>(&Qf[gq + 16 * Dd + o]);
                    const half8v b1 = *reinterpret_cast<const half8v*>(&Ef[gq + 16 * Dd + o]);
                    acc01 = MFMAH(a0, b1, acc01);
                    acc10 = MFMAH(a1, b0, acc10);
                    acc11 = MFMAH(a1, b1, acc11);
                }
            }
        }
    }

    // ---- In-register softmax + column sums ----
    const float NEG = -1e30f;
    const bool kv0 = row < L;
    const bool kv1 = (16 + row) < L;
    float cA, cB;
    {
        float w00[4], w01[4], w10[4], w11[4];
#pragma unroll
        for (int r = 0; r < 4; ++r) {
            float m = kv0 ? acc00[r] : NEG;
            if (big) m = fmaxf(m, kv1 ? acc01[r] : NEG);
#pragma unroll
            for (int st = 1; st <= 8; st <<= 1) m = fmaxf(m, __shfl_xor(m, st));
            const float e0 = kv0 ? __expf(acc00[r] - m) : 0.f;
            const float e1 = (big && kv1) ? __expf(acc01[r] - m) : 0.f;
            float sum = e0 + e1;
#pragma unroll
            for (int st = 1; st <= 8; st <<= 1) sum += __shfl_xor(sum, st);
            const float inv = 1.f / sum;
            const bool qv = (kq * 4 + r) < L;
            w00[r] = qv ? e0 * inv : 0.f;
            w01[r] = qv ? e1 * inv : 0.f;
            if (big) {
                float mh = kv0 ? acc10[r] : NEG;
                mh = fmaxf(mh, kv1 ? acc11[r] : NEG);
#pragma unroll
                for (int st = 1; st <= 8; st <<= 1) mh = fmaxf(mh, __shfl_xor(mh, st));
                const float f0 = kv0 ? __expf(acc10[r] - mh) : 0.f;
                const float f1 = kv1 ? __expf(acc11[r] - mh) : 0.f;
                float sh = f0 + f1;
#pragma unroll
                for (int st = 1; st <= 8; st <<= 1) sh += __shfl_xor(sh, st);
                const float invh = 1.f / sh;
                const bool qvh = (16 + kq * 4 + r) < L;
                w10[r] = qvh ? f0 * invh : 0.f;
                w11[r] = qvh ? f1 * invh : 0.f;
            }
        }
        float pa = w00[0] + w00[1] + w00[2] + w00[3];
        float pb = 0.f;
        if (big) {
            pa += w10[0] + w10[1] + w10[2] + w10[3];
            pb = w01[0] + w01[1] + w01[2] + w01[3] +
                 w11[0] + w11[1] + w11[2] + w11[3];
        }
        pa += __shfl_xor(pa, 16);
        pa += __shfl_xor(pa, 32);
        if (big) {
            pb += __shfl_xor(pb, 16);
            pb += __shfl_xor(pb, 32);
        }
        cA = pa;
        cB = pb;
    }

    // ---- Output: out[s][d] = sum_k c_k * E[start+k][d], fp16 reads ----
    if (active) {
        f32x4 o[3] = {};
        const int KP = (L + 3) & ~3;
        const _Float16* ebase = Ef + (size_t)start * Dd + lane * 4;
        for (int k = 0; k < KP; k += 4) {
            float cv[4];
            half4v ev[4][3];
#pragma unroll
            for (int j = 0; j < 4; ++j) {
                const int kk = k + j;
                cv[j] = (kk < 16) ? __shfl(cA, kk) : __shfl(cB, kk - 16);
#pragma unroll
                for (int i = 0; i < 3; ++i)
                    ev[j][i] = *reinterpret_cast<const half4v*>(ebase + (size_t)kk * Dd + i * 256);
            }
#pragma unroll
            for (int j = 0; j < 4; ++j)
#pragma unroll
                for (int i = 0; i < 3; ++i) {
                    o[i][0] += cv[j] * (float)ev[j][i][0];
                    o[i][1] += cv[j] * (float)ev[j][i][1];
                    o[i][2] += cv[j] * (float)ev[j][i][2];
                    o[i][3] += cv[j] * (float)ev[j][i][3];
                }
        }
#pragma unroll
        for (int i = 0; i < 3; ++i)
            *reinterpret_cast<f32x4*>(&out[(size_t)s * Dd + i * 256 + lane * 4]) = o[i];
    }
}

// ---------------------------------------------------------------------------
// Round-5 bf16 global span kernel (proven) — fallback tiers only.
// ---------------------------------------------------------------------------
template <bool SPLIT, bool SORTED>
__global__ __launch_bounds__(256) void span_attn_g_kernel(const __bf16* __restrict__ Eb,
                                                          const int* __restrict__ spans,
                                                          const __bf16* __restrict__ Qh,
                                                          const __bf16* __restrict__ Ql,
                                                          const int* __restrict__ perm,
                                                          float* __restrict__ out) {
    const int wave = threadIdx.x >> 6;
    const int lane = threadIdx.x & 63;

    int s;
    bool active;
    if (SORTED) {
        const int b    = blockIdx.x;
        const int bp   = (b & 7) * 313 + (b >> 3);
        const int slot = bp * 4 + wave;
        active = slot < Nn;
        int sv = active ? perm[slot] : 0;
        if ((unsigned)sv >= (unsigned)Nn) sv = 0;
        s = sv;
    } else {
        s = blockIdx.x * 4 + wave;
        active = true;
    }

    const int start = spans[2 * s];
    const int L     = spans[2 * s + 1] - start + 1;
    const bool big  = L > 16;

    const int row = lane & 15;
    const int kq  = lane >> 4;

    const size_t rbase = (size_t)(start + row) * Dd + kq * 8;
    const __bf16* qh0 = Qh + rbase;
    const __bf16* eb0 = Eb + rbase;
    const __bf16* ql0 = SPLIT ? (Ql + rbase) : nullptr;

    f32x4 acc00 = {0.f, 0.f, 0.f, 0.f};
    f32x4 acc01 = {0.f, 0.f, 0.f, 0.f};
    f32x4 acc10 = {0.f, 0.f, 0.f, 0.f};
    f32x4 acc11 = {0.f, 0.f, 0.f, 0.f};

    if (!big) {
        for (int kc = 0; kc < Dd; kc += 128) {
            bf16x8 A[4], B[4], AL[4];
#pragma unroll
            for (int j = 0; j < 4; ++j) {
                const int o = kc + j * 32;
                A[j] = *reinterpret_cast<const bf16x8*>(qh0 + o);
                B[j] = *reinterpret_cast<const bf16x8*>(eb0 + o);
                if (SPLIT) AL[j] = *reinterpret_cast<const bf16x8*>(ql0 + o);
            }
#pragma unroll
            for (int j = 0; j < 4; ++j) {
                acc00 = MFMA16(A[j], B[j], acc00);
                if (SPLIT) acc00 = MFMA16(AL[j], B[j], acc00);
            }
        }
    } else {
        for (int kc = 0; kc < Dd; kc += 64) {
            bf16x8 A0[2], A1[2], B0[2], B1[2], AL0[2], AL1[2];
#pragma unroll
            for (int j = 0; j < 2; ++j) {
                const int o = kc + j * 32;
                A0[j] = *reinterpret_cast<const bf16x8*>(qh0 + o);
                A1[j] = *reinterpret_cast<const bf16x8*>(qh0 + 16 * Dd + o);
                B0[j] = *reinterpret_cast<const bf16x8*>(eb0 + o);
                B1[j] = *reinterpret_cast<const bf16x8*>(eb0 + 16 * Dd + o);
                if (SPLIT) {
                    AL0[j] = *reinterpret_cast<const bf16x8*>(ql0 + o);
                    AL1[j] = *reinterpret_cast<const bf16x8*>(ql0 + 16 * Dd + o);
                }
            }
#pragma unroll
            for (int j = 0; j < 2; ++j) {
                acc00 = MFMA16(A0[j], B0[j], acc00);
                acc01 = MFMA16(A0[j], B1[j], acc01);
                acc10 = MFMA16(A1[j], B0[j], acc10);
                acc11 = MFMA16(A1[j], B1[j], acc11);
                if (SPLIT) {
                    acc00 = MFMA16(AL0[j], B0[j], acc00);
                    acc01 = MFMA16(AL0[j], B1[j], acc01);
                    acc10 = MFMA16(AL1[j], B0[j], acc10);
                    acc11 = MFMA16(AL1[j], B1[j], acc11);
                }
            }
        }
    }

    const float NEG = -1e30f;
    const bool kv0 = row < L;
    const bool kv1 = (16 + row) < L;
    float cA, cB;
    {
        float w00[4], w01[4], w10[4], w11[4];
#pragma unroll
        for (int r = 0; r < 4; ++r) {
            float m = kv0 ? acc00[r] : NEG;
            if (big) m = fmaxf(m, kv1 ? acc01[r] : NEG);
#pragma unroll
            for (int st = 1; st <= 8; st <<= 1) m = fmaxf(m, __shfl_xor(m, st));
            const float e0 = kv0 ? __expf(acc00[r] - m) : 0.f;
            const float e1 = (big && kv1) ? __expf(acc01[r] - m) : 0.f;
            float sum = e0 + e1;
#pragma unroll
            for (int st = 1; st <= 8; st <<= 1) sum += __shfl_xor(sum, st);
            const float inv = 1.f / sum;
            const bool qv = (kq * 4 + r) < L;
            w00[r] = qv ? e0 * inv : 0.f;
            w01[r] = qv ? e1 * inv : 0.f;
            if (big) {
                float mh = kv0 ? acc10[r] : NEG;
                mh = fmaxf(mh, kv1 ? acc11[r] : NEG);
#pragma unroll
                for (int st = 1; st <= 8; st <<= 1) mh = fmaxf(mh, __shfl_xor(mh, st));
                const float f0 = kv0 ? __expf(acc10[r] - mh) : 0.f;
                const float f1 = kv1 ? __expf(acc11[r] - mh) : 0.f;
                float sh = f0 + f1;
#pragma unroll
                for (int st = 1; st <= 8; st <<= 1) sh += __shfl_xor(sh, st);
                const float invh = 1.f / sh;
                const bool qvh = (16 + kq * 4 + r) < L;
                w10[r] = qvh ? f0 * invh : 0.f;
                w11[r] = qvh ? f1 * invh : 0.f;
            }
        }
        float pa = w00[0] + w00[1] + w00[2] + w00[3];
        float pb = 0.f;
        if (big) {
            pa += w10[0] + w10[1] + w10[2] + w10[3];
            pb = w01[0] + w01[1] + w01[2] + w01[3] +
                 w11[0] + w11[1] + w11[2] + w11[3];
        }
        pa += __shfl_xor(pa, 16);
        pa += __shfl_xor(pa, 32);
        if (big) {
            pb += __shfl_xor(pb, 16);
            pb += __shfl_xor(pb, 32);
        }
        cA = pa;
        cB = pb;
    }

    if (active) {
        f32x4 o[3] = {};
        const int KP = (L + 3) & ~3;
        const __bf16* ebase = Eb + (size_t)start * Dd + lane * 4;
        for (int k = 0; k < KP; k += 4) {
            float cv[4];
            bf16x4 ev[4][3];
#pragma unroll
            for (int j = 0; j < 4; ++j) {
                const int kk = k + j;
                cv[j] = (kk < 16) ? __shfl(cA, kk) : __shfl(cB, kk - 16);
#pragma unroll
                for (int i = 0; i < 3; ++i)
                    ev[j][i] = *reinterpret_cast<const bf16x4*>(ebase + (size_t)kk * Dd + i * 256);
            }
#pragma unroll
            for (int j = 0; j < 4; ++j)
#pragma unroll
                for (int i = 0; i < 3; ++i) {
                    o[i][0] += cv[j] * (float)ev[j][i][0];
                    o[i][1] += cv[j] * (float)ev[j][i][1];
                    o[i][2] += cv[j] * (float)ev[j][i][2];
                    o[i][3] += cv[j] * (float)ev[j][i][3];
                }
        }
#pragma unroll
        for (int i = 0; i < 3; ++i)
            *reinterpret_cast<f32x4*>(&out[(size_t)s * Dd + i * 256 + lane * 4]) = o[i];
    }
}

// ---------------------------------------------------------------------------
extern "C" void kernel_launch(void* const* d_in, const int* in_sizes, int n_in,
                              void* d_out, int out_size, void* d_ws, size_t ws_size,
                              hipStream_t stream) {
    const float* emb   = (const float*)d_in[0];
    const int*   spans = (const int*)d_in[1];
    const float* Wq    = (const float*)d_in[2];
    const float* bq    = (const float*)d_in[3];
    float*       out   = (float*)d_out;

    const size_t TD = (size_t)Tt * Dd;
    const size_t DD = (size_t)Dd * Dd;
    const size_t intBytes = (size_t)(8192 + 10016) * sizeof(int);
    auto align16 = [](size_t x) { return (x + 15) & ~(size_t)15; };

    const size_t needMain = align16((2 * TD + DD) * 2) + intBytes;  // ~26.6 MB
    const size_t needB = align16(3 * TD * 2) + intBytes;
    const size_t needC = 3 * TD * 2;

    if (ws_size >= needMain) {
        char* base = (char*)d_ws;
        _Float16* Qf = (_Float16*)base;
        _Float16* Ef = (_Float16*)(base + TD * 2);
        _Float16* Wf = (_Float16*)(base + 2 * TD * 2);
        int* hist = (int*)(base + align16((2 * TD + DD) * 2));
        int* perm = hist + 8192;

        const int convBlocks = (int)((TD / 4 + DD / 4) / 256);  // 6720 exact
        conv_f16_kernel<<<convBlocks, 256, 0, stream>>>(emb, Wq, Ef, Wf);
        zero_kernel<<<32, 256, 0, stream>>>(hist, 8192);
        hist_kernel<<<40, 256, 0, stream>>>(spans, hist);
        scan_kernel<<<1, 256, 0, stream>>>(hist);
        scatter_kernel<<<40, 256, 0, stream>>>(spans, hist, perm);
        qproj_f16_kernel<<<1024, 256, 0, stream>>>(Ef, Wf, bq, Qf);
        span_attn_win_kernel<<<2504, 256, 0, stream>>>(Ef, spans, Qf, perm, out);
    } else if (ws_size >= needB) {
        __bf16* w = (__bf16*)d_ws;
        __bf16* Qh = w;
        __bf16* Ql = w + TD;
        __bf16* Eh = w + 2 * TD;
        int* hist = (int*)((char*)d_ws + align16(3 * TD * 2));
        int* perm = hist + 8192;

        conv_kernel<false><<<(int)(TD / 4 / 256), 256, 0, stream>>>(emb, Eh, nullptr, (int)(TD / 4));
        zero_kernel<<<32, 256, 0, stream>>>(hist, 8192);
        hist_kernel<<<40, 256, 0, stream>>>(spans, hist);
        scan_kernel<<<1, 256, 0, stream>>>(hist);
        scatter_kernel<<<40, 256, 0, stream>>>(spans, hist, perm);
        qproj_kernel<true><<<dim3(Tt / 64, Dd / 64), 256, 0, stream>>>(emb, Wq, bq, Qh, Ql);
        span_attn_g_kernel<true, true><<<2504, 256, 0, stream>>>(Eh, spans, Qh, Ql, perm, out);
    } else if (ws_size >= needC) {
        __bf16* w = (__bf16*)d_ws;
        __bf16* Qh = w;
        __bf16* Ql = w + TD;
        __bf16* Eh = w + 2 * TD;
        conv_kernel<false><<<(int)(TD / 4 / 256), 256, 0, stream>>>(emb, Eh, nullptr, (int)(TD / 4));
        qproj_kernel<true><<<dim3(Tt / 64, Dd / 64), 256, 0, stream>>>(emb, Wq, bq, Qh, Ql);
        span_attn_g_kernel<true, false><<<2500, 256, 0, stream>>>(Eh, spans, Qh, Ql, nullptr, out);
    } else {
        __bf16* w = (__bf16*)d_ws;
        __bf16* Qh = w;
        __bf16* Eh = w + TD;
        conv_kernel<false><<<(int)(TD / 4 / 256), 256, 0, stream>>>(emb, Eh, nullptr, (int)(TD / 4));
        qproj_kernel<false><<<dim3(Tt / 64, Dd / 64), 256, 0, stream>>>(emb, Wq, bq, Qh, nullptr);
        span_attn_g_kernel<false, false><<<2500, 256, 0, stream>>>(Eh, spans, Qh, nullptr, nullptr, out);
    }
}